// Round 3
// baseline (2519.584 us; speedup 1.0000x reference)
//
#include <hip/hip_runtime.h>
#include <cmath>

#define BB 8
#define DD 1024
#define NP 4096
#define KC 32
#define HH 512
#define PP 128
#define NJB 16          // sinkhorn blocks per batch
#define NBLK_SINK (BB * NJB)
#define BN_EPS 1e-5f

typedef unsigned short u16;
typedef short s16x8 __attribute__((ext_vector_type(8)));
typedef float f32x4 __attribute__((ext_vector_type(4)));

// ---------------- wave helpers ----------------
__device__ __forceinline__ float waveReduceSum(float v) {
#pragma unroll
  for (int o = 32; o > 0; o >>= 1) v += __shfl_down(v, o, 64);
  return v;
}

// ---------------- device-scope grid barrier (all blocks co-resident) ------
// release: per-thread __threadfence before arrival; releaser bumps gen after
// fencing the counter reset. acquire: fence after observing gen bump.
__device__ __forceinline__ void gridBar(unsigned* cnt, unsigned* gen, unsigned nblk) {
  __threadfence();
  __syncthreads();
  if (threadIdx.x == 0) {
    unsigned g = atomicAdd(gen, 0u);           // accurate device-scope read
    if (atomicAdd(cnt, 1u) == nblk - 1u) {
      atomicExch(cnt, 0u);
      __threadfence();
      atomicAdd(gen, 1u);
    } else {
      while (atomicAdd(gen, 0u) == g) __builtin_amdgcn_s_sleep(8);
    }
  }
  __syncthreads();
  __threadfence();
}

// ---------------- bf16 3-way split: y = h + m + l + O(2^-24 |y|) ----------
__device__ __forceinline__ void split3(float y, short& h, short& m, short& l) {
  unsigned uy = __float_as_uint(y);
  h = (short)(uy >> 16);
  float r1 = y - __uint_as_float(uy & 0xFFFF0000u);
  unsigned um = __float_as_uint(r1);
  m = (short)(um >> 16);
  float r2 = r1 - __uint_as_float(um & 0xFFFF0000u);
  l = (short)(__float_as_uint(r2) >> 16);
}

// ---------------- W pre-permute + 3-split, all three weight sets in one launch
__global__ __launch_bounds__(256) void convW3_all(
    const float* __restrict__ W1, u16* __restrict__ h1, u16* __restrict__ m1, u16* __restrict__ l1,
    const float* __restrict__ W2, u16* __restrict__ h2, u16* __restrict__ m2, u16* __restrict__ l2,
    const float* __restrict__ W3, u16* __restrict__ h3, u16* __restrict__ m3, u16* __restrict__ l3) {
  int z = blockIdx.z;
  const float* W; u16 *hb, *mb, *lb; int K, BM, MTt, KCH;
  if (z == 0)      { W = W1; hb = h1; mb = m1; lb = l1; K = 1024; BM = 128; MTt = 4; KCH = 32; }
  else if (z == 1) { W = W2; hb = h2; mb = m2; lb = l2; K = 512;  BM = 128; MTt = 4; KCH = 16; }
  else             { W = W3; hb = h3; mb = m3; lb = l3; K = 512;  BM = 32;  MTt = 1; KCH = 16; }
  int mt = blockIdx.x, kc = blockIdx.y;
  if (mt >= MTt || kc >= KCH) return;
  const int AU = BM * 4;
  for (int u = threadIdx.x; u < AU; u += 256) {
    int q = u / BM, m = u % BM;
    const float* wp = W + (size_t)(mt * BM + m) * K + kc * 32 + q * 8;
    s16x8 hv, mv, lv;
#pragma unroll
    for (int j = 0; j < 8; j++) {
      short h, mm, l; split3(wp[j], h, mm, l);
      hv[j] = h; mv[j] = mm; lv[j] = l;
    }
    size_t ob = ((size_t)(mt * KCH + kc)) * (size_t)(BM * 32) + (size_t)u * 8;
    *(s16x8*)(hb + ob) = hv;
    *(s16x8*)(mb + ob) = mv;
    *(s16x8*)(lb + ob) = lv;
  }
}

// ---------------- bf16x3 MFMA GEMM (f32-equivalent), reg-prefetch pipelined
template<int BM, int MBLK, int MT, int NT, int WM, bool BNRELU>
__global__ __launch_bounds__(256) void gemm_mfma3(
    const u16* __restrict__ wh, const u16* __restrict__ wmid, const u16* __restrict__ wl,
    const float* __restrict__ bias, const float* __restrict__ X,
    const float* __restrict__ bnsc, const float* __restrict__ bnsh,
    float* __restrict__ Y, int K, int M) {
  __shared__ s16x8 AhS[BM * 4], AmS[BM * 4], AlS[BM * 4];
  __shared__ s16x8 BhS[512], BmS[512], BlS[512];
  const int KCH = K / 32;
  const int tid = threadIdx.x;
  const int bz = blockIdx.z;
  int bid = blockIdx.x;
  int xs = bid & 7, rr = bid >> 3;
  int m_idx = rr % MBLK;
  int n_idx = xs + 8 * (rr / MBLK);

  const int w = tid >> 6, l = tid & 63, q = l >> 4, col = l & 15;
  const int wm = (WM == 1) ? 0 : (w >> 1);
  const int wn = (WM == 1) ? w : (w & 1);
  constexpr int NA = (BM * 4 + 255) / 256;

  f32x4 acc[MT][NT];
#pragma unroll
  for (int i = 0; i < MT; i++)
#pragma unroll
    for (int j = 0; j < NT; j++) { acc[i][j][0] = 0.f; acc[i][j][1] = 0.f; acc[i][j][2] = 0.f; acc[i][j][3] = 0.f; }

  const short* Ah = (const short*)AhS;
  const short* Am = (const short*)AmS;
  const short* Al = (const short*)AlS;
  const short* Bh = (const short*)BhS;
  const short* Bm = (const short*)BmS;
  const short* Bl = (const short*)BlS;

  const float* Xb = X + (size_t)bz * (size_t)K * NP + (size_t)n_idx * 128;
  const size_t abase = (size_t)m_idx * KCH * (size_t)(BM * 32);

  s16x8 rAh[NA], rAm[NA], rAl[NA];
  float rB[2][8];

  {
    const s16x8* awh = (const s16x8*)(wh + abase);
    const s16x8* awm = (const s16x8*)(wmid + abase);
    const s16x8* awl = (const s16x8*)(wl + abase);
#pragma unroll
    for (int t = 0; t < NA; t++) {
      int u = tid + t * 256;
      if (u < BM * 4) { rAh[t] = awh[u]; rAm[t] = awm[u]; rAl[t] = awl[u]; }
    }
#pragma unroll
    for (int t = 0; t < 2; t++) {
      int u = tid + t * 256;
      int qq = u >> 7, n = u & 127;
      const float* fp = Xb + (size_t)(qq * 8) * NP + n;
#pragma unroll
      for (int j = 0; j < 8; j++) {
        float y = fp[(size_t)j * NP];
        if (BNRELU) y = fmaxf(fmaf(y, bnsc[qq * 8 + j], bnsh[qq * 8 + j]), 0.f);
        rB[t][j] = y;
      }
    }
  }

  for (int kc = 0; kc < KCH; kc++) {
#pragma unroll
    for (int t = 0; t < NA; t++) {
      int u = tid + t * 256;
      if (u < BM * 4) { AhS[u] = rAh[t]; AmS[u] = rAm[t]; AlS[u] = rAl[t]; }
    }
#pragma unroll
    for (int t = 0; t < 2; t++) {
      int u = tid + t * 256;
      s16x8 hv, mv, lv;
#pragma unroll
      for (int j = 0; j < 8; j++) {
        short h, mm, ll; split3(rB[t][j], h, mm, ll);
        hv[j] = h; mv[j] = mm; lv[j] = ll;
      }
      BhS[u] = hv; BmS[u] = mv; BlS[u] = lv;
    }
    __syncthreads();

    if (kc + 1 < KCH) {
      size_t ab = abase + (size_t)(kc + 1) * (size_t)(BM * 32);
      const s16x8* awh = (const s16x8*)(wh + ab);
      const s16x8* awm = (const s16x8*)(wmid + ab);
      const s16x8* awl = (const s16x8*)(wl + ab);
#pragma unroll
      for (int t = 0; t < NA; t++) {
        int u = tid + t * 256;
        if (u < BM * 4) { rAh[t] = awh[u]; rAm[t] = awm[u]; rAl[t] = awl[u]; }
      }
      const int kp = (kc + 1) * 32;
#pragma unroll
      for (int t = 0; t < 2; t++) {
        int u = tid + t * 256;
        int qq = u >> 7, n = u & 127;
        const float* fp = Xb + (size_t)(kp + qq * 8) * NP + n;
#pragma unroll
        for (int j = 0; j < 8; j++) {
          float y = fp[(size_t)j * NP];
          if (BNRELU) y = fmaxf(fmaf(y, bnsc[kp + qq * 8 + j], bnsh[kp + qq * 8 + j]), 0.f);
          rB[t][j] = y;
        }
      }
    }

    s16x8 ah[MT], am[MT], al[MT];
#pragma unroll
    for (int i = 0; i < MT; i++) {
      int off = (q * BM + wm * (MT * 16) + i * 16 + col) * 8;
      ah[i] = *(const s16x8*)(Ah + off);
      am[i] = *(const s16x8*)(Am + off);
      al[i] = *(const s16x8*)(Al + off);
    }
    __builtin_amdgcn_s_setprio(1);
#pragma unroll
    for (int j = 0; j < NT; j++) {
      int offb = (q * 128 + wn * (NT * 16) + j * 16 + col) * 8;
      s16x8 bh = *(const s16x8*)(Bh + offb);
      s16x8 bm = *(const s16x8*)(Bm + offb);
      s16x8 bl = *(const s16x8*)(Bl + offb);
#pragma unroll
      for (int i = 0; i < MT; i++) {
        acc[i][j] = __builtin_amdgcn_mfma_f32_16x16x32_bf16(ah[i], bh, acc[i][j], 0, 0, 0);
        acc[i][j] = __builtin_amdgcn_mfma_f32_16x16x32_bf16(ah[i], bm, acc[i][j], 0, 0, 0);
        acc[i][j] = __builtin_amdgcn_mfma_f32_16x16x32_bf16(am[i], bh, acc[i][j], 0, 0, 0);
        acc[i][j] = __builtin_amdgcn_mfma_f32_16x16x32_bf16(ah[i], bl, acc[i][j], 0, 0, 0);
        acc[i][j] = __builtin_amdgcn_mfma_f32_16x16x32_bf16(am[i], bm, acc[i][j], 0, 0, 0);
        acc[i][j] = __builtin_amdgcn_mfma_f32_16x16x32_bf16(al[i], bh, acc[i][j], 0, 0, 0);
      }
    }
    __builtin_amdgcn_s_setprio(0);
    __syncthreads();
  }
#pragma unroll
  for (int i = 0; i < MT; i++) {
#pragma unroll
    for (int r = 0; r < 4; r++) {
      int m = m_idx * BM + wm * (MT * 16) + i * 16 + q * 4 + r;
      float bv = bias[m];
#pragma unroll
      for (int j = 0; j < NT; j++) {
        int n = n_idx * 128 + wn * (NT * 16) + j * 16 + col;
        Y[((size_t)bz * M + m) * 4096 + n] = acc[i][j][r] + bv;
      }
    }
  }
}

// ---------------- BN (training, batch stats over B and N) per channel
__global__ __launch_bounds__(256) void bnstats(
    const float* __restrict__ Y, const float* __restrict__ g, const float* __restrict__ beta,
    float* __restrict__ scale, float* __restrict__ shift, int C, int N) {
  int c = blockIdx.x;
  float s = 0.f, sq = 0.f;
  for (int b = 0; b < BB; b++) {
    const float* p = Y + ((size_t)b * C + c) * N;
    for (int n = threadIdx.x; n < N; n += 256) { float v = p[n]; s += v; sq += v * v; }
  }
  __shared__ float shs[4], shq[4];
  int lane = threadIdx.x & 63, wid = threadIdx.x >> 6;
  s = waveReduceSum(s); sq = waveReduceSum(sq);
  if (lane == 0) { shs[wid] = s; shq[wid] = sq; }
  __syncthreads();
  if (threadIdx.x == 0) {
    float S = shs[0] + shs[1] + shs[2] + shs[3];
    float Q = shq[0] + shq[1] + shq[2] + shq[3];
    float cnt = (float)(BB * N);
    float mean = S / cnt;
    float var = Q / cnt - mean * mean;
    float sc = g[c] / sqrtf(var + BN_EPS);
    scale[c] = sc; shift[c] = beta[c] - mean * sc;
  }
}

// ---------------- softmax over K (axis=1), write score, lse per (b,n), pi partial sums
__global__ __launch_bounds__(256) void softmax_pi(
    const float* __restrict__ LSm, float* __restrict__ score,
    float* __restrict__ lseArr, float* __restrict__ pi_raw) {
  int gidx = blockIdx.x * 256 + threadIdx.x;
  int b = gidx / NP, n = gidx % NP;
  const float* p = LSm + (size_t)b * KC * NP + n;
  float v[KC];
  float m = -1e30f;
#pragma unroll
  for (int k = 0; k < KC; k++) { v[k] = p[(size_t)k * NP]; m = fmaxf(m, v[k]); }
  float s = 0.f;
#pragma unroll
  for (int k = 0; k < KC; k++) { v[k] = expf(v[k] - m); s += v[k]; }
  float inv = 1.f / s;
  float* qq = score + (size_t)b * KC * NP + n;
#pragma unroll
  for (int k = 0; k < KC; k++) { v[k] *= inv; qq[(size_t)k * NP] = v[k]; }
  lseArr[gidx] = m + logf(s);
  __shared__ float ps[KC];
  if (threadIdx.x < KC) ps[threadIdx.x] = 0.f;
  __syncthreads();
  int lane = threadIdx.x & 63;
#pragma unroll
  for (int k = 0; k < KC; k++) {
    float w = waveReduceSum(v[k]);
    if (lane == 0) atomicAdd(&ps[k], w);
  }
  __syncthreads();
  if (threadIdx.x < KC) atomicAdd(&pi_raw[b * KC + threadIdx.x], ps[threadIdx.x]);
}

// ---------------- vlad accumulation (split over n, atomic)
__global__ __launch_bounds__(256) void vlad_accum(
    const float* __restrict__ feat, const float* __restrict__ score, float* __restrict__ vlad) {
  const int SPLIT_LEN = NP / 8;
  int sp = blockIdx.x, dt = blockIdx.y, b = blockIdx.z;
  int d0 = dt * 128;
  int n_start = sp * SPLIT_LEN;
  __shared__ float As[32][132];
  __shared__ float Bs[32][36];
  int tid = threadIdx.x;
  int tx = tid % 16;
  int ty = tid / 16;
  float acc[8][2] = {};
  const float* fb = feat + (size_t)b * DD * NP;
  const float* sb = score + (size_t)b * KC * NP;
  for (int nc = 0; nc < SPLIT_LEN; nc += 32) {
    int n0 = n_start + nc;
    for (int i = tid; i < 128 * 32; i += 256) {
      int r = i >> 5, c = i & 31;
      As[c][r] = fb[(size_t)(d0 + r) * NP + n0 + c];
    }
    for (int i = tid; i < 32 * 32; i += 256) {
      int r = i >> 5, c = i & 31;
      Bs[c][r] = sb[(size_t)r * NP + n0 + c];
    }
    __syncthreads();
#pragma unroll 4
    for (int kk = 0; kk < 32; kk++) {
      float ra[8], rb[2];
#pragma unroll
      for (int i = 0; i < 8; i++) ra[i] = As[kk][ty * 8 + i];
      rb[0] = Bs[kk][tx * 2]; rb[1] = Bs[kk][tx * 2 + 1];
#pragma unroll
      for (int i = 0; i < 8; i++) { acc[i][0] = fmaf(ra[i], rb[0], acc[i][0]); acc[i][1] = fmaf(ra[i], rb[1], acc[i][1]); }
    }
    __syncthreads();
  }
#pragma unroll
  for (int i = 0; i < 8; i++)
#pragma unroll
    for (int j = 0; j < 2; j++)
      atomicAdd(&vlad[((size_t)b * DD + d0 + ty * 8 + i) * KC + tx * 2 + j], acc[i][j]);
}

// ---------------- vlad finalize + gmax + fused ||mu_k||^2 partials
__global__ __launch_bounds__(256) void vlad_fin(
    float* __restrict__ vlad, const float* __restrict__ pi_raw, float* __restrict__ gmax,
    float* __restrict__ nmusq) {
  int idx = blockIdx.x * 256 + threadIdx.x;
  int b = idx / DD;
  float* p = vlad + (size_t)idx * KC;
  const float* pr = pi_raw + b * KC;
  float gm = -1e30f;
  __shared__ float wk[4][KC];
  int lane = threadIdx.x & 63, wid = threadIdx.x >> 6;
#pragma unroll
  for (int k = 0; k < KC; k++) {
    float v = p[k] / fmaxf(pr[k], 1e-4f);
    p[k] = v;
    gm = fmaxf(gm, v);
    float s2 = waveReduceSum(v * v);
    if (lane == 0) wk[wid][k] = s2;
  }
  gmax[idx] = gm;
  __syncthreads();
  if (threadIdx.x < KC) {
    float t = wk[0][threadIdx.x] + wk[1][threadIdx.x] + wk[2][threadIdx.x] + wk[3][threadIdx.x];
    atomicAdd(&nmusq[b * KC + threadIdx.x], t);
  }
}

// ---------------- cost dot accumulation (split over d, atomic) + fused ||f_n||^2
__global__ __launch_bounds__(256) void cost_accum(
    const float* __restrict__ feat, const float* __restrict__ vlad, float* __restrict__ costd,
    float* __restrict__ nfsq) {
  int sp = blockIdx.x, nt = blockIdx.y, b = blockIdx.z;
  int n0 = nt * 128;
  int d_start = sp * (DD / 4);
  __shared__ float As[32][132];
  __shared__ float Bs[32][36];
  __shared__ float nfs[128];
  int tid = threadIdx.x;
  int tx = tid % 16;
  int ty = tid / 16;
  float acc[8][2] = {};
  float sq = 0.f;
  const float* fb = feat + (size_t)b * DD * NP;
  const float* vb = vlad + (size_t)b * DD * KC;
  for (int dc = 0; dc < DD / 4; dc += 32) {
    int dd0 = d_start + dc;
    for (int i = tid; i < 32 * 128; i += 256) {
      int r = i >> 7, c = i & 127;
      float v = fb[(size_t)(dd0 + r) * NP + n0 + c];
      As[r][c] = v;
      sq = fmaf(v, v, sq);
    }
    for (int i = tid; i < 32 * 32; i += 256) {
      int r = i >> 5, c = i & 31;
      Bs[r][c] = vb[(size_t)(dd0 + r) * KC + c];
    }
    __syncthreads();
#pragma unroll 4
    for (int kk = 0; kk < 32; kk++) {
      float ra[8], rb[2];
#pragma unroll
      for (int i = 0; i < 8; i++) ra[i] = As[kk][ty * 8 + i];
      rb[0] = Bs[kk][tx * 2]; rb[1] = Bs[kk][tx * 2 + 1];
#pragma unroll
      for (int i = 0; i < 8; i++) { acc[i][0] = fmaf(ra[i], rb[0], acc[i][0]); acc[i][1] = fmaf(ra[i], rb[1], acc[i][1]); }
    }
    __syncthreads();
  }
#pragma unroll
  for (int i = 0; i < 8; i++)
#pragma unroll
    for (int j = 0; j < 2; j++)
      atomicAdd(&costd[((size_t)b * NP + n0 + ty * 8 + i) * KC + tx * 2 + j], acc[i][j]);
  if (tid < 128) nfs[tid] = 0.f;
  __syncthreads();
  atomicAdd(&nfs[tid & 127], sq);
  __syncthreads();
  if (tid < 128) atomicAdd(&nfsq[(size_t)b * NP + n0 + tid], nfs[tid]);
}

// ---------------- fused sinkhorn: cost_fin + 25 iterations + loss, ONE launch
// 128 blocks (16 per b, 256 rows each). Each thread keeps its normalized cost
// row (32 f32) in registers for all 25 iterations. Cross-block v-reduction via
// the same G partial scheme as before, grid barrier replaces kernel relaunch.
__global__ __launch_bounds__(256) void sinkhorn_all(
    const float* __restrict__ costd, const float* __restrict__ nfsq,
    const float* __restrict__ nmusq, float* __restrict__ G,
    const float* __restrict__ LSm, const float* __restrict__ lseArr,
    float* __restrict__ out0, unsigned* __restrict__ bar,
    float logp, float logq) {
  const float EPS = 1e-3f, IEPS = 1000.f;
  int b = blockIdx.x / NJB, j = blockIdx.x % NJB;
  int tid = threadIdx.x;
  int n = j * 256 + tid;
  __shared__ float vsh[KC];
  __shared__ float nmS[KC];
  __shared__ float vals[256][33];   // (u - c)/eps staging, +1 pad -> 2-way max
  __shared__ float red[KC][9];      // 8 segment partials per k
  __shared__ float bmS[KC];
  __shared__ float redL[4];

  if (tid < KC) nmS[tid] = fmaxf(sqrtf(nmusq[b * KC + tid]), 1e-12f);
  __syncthreads();

  // load + normalize this thread's cost row into registers (cost_fin folded)
  float c[KC];
  {
    const float* dp = costd + ((size_t)b * NP + n) * KC;
    float nf = fmaxf(sqrtf(nfsq[(size_t)b * NP + n]), 1e-12f);
#pragma unroll
    for (int k = 0; k < KC; k++) c[k] = 2.f - 2.f * dp[k] / (nf * nmS[k]);
  }

  const int kk = tid & 31, seg = tid >> 5;   // reduction mapping: 8 segs x 32 rows
  const int r0 = seg * 32;
  float u = 0.f;

  for (int t = 1; t <= 25; t++) {
    if (tid < KC) {
      float v = 0.f;
      if (t > 1) {
        const float* Gp = G + (((size_t)(t - 2) * BB + b) * NJB) * KC * 2;
        float m = -1e30f;
        for (int jj = 0; jj < NJB; jj++) m = fmaxf(m, Gp[(jj * KC + tid) * 2]);
        float s = 0.f;
        for (int jj = 0; jj < NJB; jj++) s += Gp[(jj * KC + tid) * 2 + 1] * expf(Gp[(jj * KC + tid) * 2] - m);
        v = EPS * logq - EPS * (m + logf(s));
      }
      vsh[tid] = v;
    }
    __syncthreads();
    // u update for this thread's row (all from regs/LDS-broadcast)
    float m = -1e30f;
#pragma unroll
    for (int k = 0; k < KC; k++) m = fmaxf(m, vsh[k] - c[k]);
    float s = 0.f;
#pragma unroll
    for (int k = 0; k < KC; k++) s += expf((vsh[k] - c[k] - m) * IEPS);
    u = EPS * logp - m - EPS * logf(s);
    // stage scaled values for the per-k block reduction
#pragma unroll
    for (int k = 0; k < KC; k++) vals[tid][k] = (u - c[k]) * IEPS;
    __syncthreads();
    // per-k max over this block's 256 rows (8 segments of 32)
    {
      float lm = -1e30f;
      for (int r = 0; r < 32; r++) lm = fmaxf(lm, vals[r0 + r][kk]);
      red[kk][seg] = lm;
    }
    __syncthreads();
    if (tid < KC) {
      float bm = red[tid][0];
      for (int i2 = 1; i2 < 8; i2++) bm = fmaxf(bm, red[tid][i2]);
      bmS[tid] = bm;
    }
    __syncthreads();
    {
      float bm = bmS[kk];
      float ls = 0.f;
      for (int r = 0; r < 32; r++) ls += expf(vals[r0 + r][kk] - bm);
      red[kk][seg] = ls;
    }
    __syncthreads();
    if (tid < KC) {
      float s8 = 0.f;
      for (int i2 = 0; i2 < 8; i2++) s8 += red[tid][i2];
      float* Gp = G + ((((size_t)(t - 1) * BB + b) * NJB + j) * KC + tid) * 2;
      Gp[0] = bmS[tid]; Gp[1] = s8;
    }
    gridBar(bar, bar + 1, NBLK_SINK);
  }

  // ---- loss: u currently holds u25 (computed from v24 in iteration 25)
  __shared__ float v25S[KC];
  if (tid < KC) {
    const float* Gp = G + (((size_t)24 * BB + b) * NJB) * KC * 2;
    float m = -1e30f;
    for (int jj = 0; jj < NJB; jj++) m = fmaxf(m, Gp[(jj * KC + tid) * 2]);
    float s = 0.f;
    for (int jj = 0; jj < NJB; jj++) s += Gp[(jj * KC + tid) * 2 + 1] * expf(Gp[(jj * KC + tid) * 2] - m);
    v25S[tid] = EPS * logq - EPS * (m + logf(s));
  }
  __syncthreads();
  float lsev = lseArr[(size_t)b * NP + n];
  float part = 0.f;
#pragma unroll
  for (int k = 0; k < KC; k++) {
    float gamma = expf((u + v25S[k] - c[k]) * IEPS);
    float logsm = LSm[((size_t)b * KC + k) * NP + n] - lsev;
    part += gamma * logsm;
  }
  part *= (float)NP;
  int lane = tid & 63, wid = tid >> 6;
  part = waveReduceSum(part);
  if (lane == 0) redL[wid] = part;
  __syncthreads();
  if (tid == 0) {
    float tt = redL[0] + redL[1] + redL[2] + redL[3];
    atomicAdd(out0, -tt / (float)(BB * NP));
  }
}

// ---------------- fused predictor MLP: 3 layers + 2 batch-norms, one block
__global__ __launch_bounds__(1024) void mlp_fused(
    const float* __restrict__ mw1, const float* __restrict__ mb1,
    const float* __restrict__ mg1, const float* __restrict__ mt1,
    const float* __restrict__ mw2, const float* __restrict__ mb2,
    const float* __restrict__ mg2, const float* __restrict__ mt2,
    const float* __restrict__ mw3, const float* __restrict__ mb3,
    const float* __restrict__ gmax, float* __restrict__ outp) {
  __shared__ float inS[BB * DD];   // 32 KiB
  __shared__ float h1[BB * HH];    // 16 KiB
  __shared__ float h2[BB * HH];    // 16 KiB
  __shared__ float scS[HH], shS[HH];
  int tid = threadIdx.x;
  for (int i = tid; i < BB * DD; i += 1024) inS[i] = gmax[i];
  __syncthreads();
  // layer 1: lanes share s (broadcast input), consecutive jj rows of W
  for (int idx = tid; idx < BB * HH; idx += 1024) {
    int s = idx >> 9, jj = idx & (HH - 1);
    const float4* wp = (const float4*)(mw1 + (size_t)jj * DD);
    const float4* ip = (const float4*)(inS + s * DD);
    float acc = 0.f;
    for (int c4 = 0; c4 < DD / 4; c4++) {
      float4 w = wp[c4]; float4 x = ip[c4];
      acc += w.x * x.x + w.y * x.y + w.z * x.z + w.w * x.w;
    }
    h1[idx] = acc + mb1[jj];
  }
  __syncthreads();
  if (tid < HH) {
    float s_ = 0.f, q = 0.f;
    for (int si = 0; si < BB; si++) { float v = h1[si * HH + tid]; s_ += v; q += v * v; }
    float mean = s_ / (float)BB, var = q / (float)BB - mean * mean;
    float sv = mg1[tid] / sqrtf(var + BN_EPS);
    scS[tid] = sv; shS[tid] = mt1[tid] - mean * sv;
  }
  __syncthreads();
  for (int i = tid; i < BB * HH; i += 1024) {
    int jj = i & (HH - 1);
    h1[i] = fmaxf(fmaf(h1[i], scS[jj], shS[jj]), 0.f);
  }
  __syncthreads();
  // layer 2
  for (int idx = tid; idx < BB * HH; idx += 1024) {
    int s = idx >> 9, jj = idx & (HH - 1);
    const float4* wp = (const float4*)(mw2 + (size_t)jj * HH);
    const float4* ip = (const float4*)(h1 + s * HH);
    float acc = 0.f;
    for (int c4 = 0; c4 < HH / 4; c4++) {
      float4 w = wp[c4]; float4 x = ip[c4];
      acc += w.x * x.x + w.y * x.y + w.z * x.z + w.w * x.w;
    }
    h2[idx] = acc + mb2[jj];
  }
  __syncthreads();
  if (tid < HH) {
    float s_ = 0.f, q = 0.f;
    for (int si = 0; si < BB; si++) { float v = h2[si * HH + tid]; s_ += v; q += v * v; }
    float mean = s_ / (float)BB, var = q / (float)BB - mean * mean;
    float sv = mg2[tid] / sqrtf(var + BN_EPS);
    scS[tid] = sv; shS[tid] = mt2[tid] - mean * sv;
  }
  __syncthreads();
  for (int i = tid; i < BB * HH; i += 1024) {
    int jj = i & (HH - 1);
    h2[i] = fmaxf(fmaf(h2[i], scS[jj], shS[jj]), 0.f);
  }
  __syncthreads();
  // layer 3: exactly 1024 outputs
  {
    int s = tid >> 7, jj = tid & (PP - 1);
    const float4* wp = (const float4*)(mw3 + (size_t)jj * HH);
    const float4* ip = (const float4*)(h2 + s * HH);
    float acc = 0.f;
    for (int c4 = 0; c4 < HH / 4; c4++) {
      float4 w = wp[c4]; float4 x = ip[c4];
      acc += w.x * x.x + w.y * x.y + w.z * x.z + w.w * x.w;
    }
    outp[tid] = acc + mb3[jj];
  }
}

// ---------------- tiled f32 conv1x1 GEMM (projector head, N=32 tiny)
template<int BM, int BN, int BK, int TM, int TN, bool BNRELU>
__global__ __launch_bounds__(256) void gemm_conv(
    const float* __restrict__ W, const float* __restrict__ bias,
    const float* __restrict__ X, float* __restrict__ Y,
    const float* __restrict__ bnscale, const float* __restrict__ bnshift,
    int M, int K, int N) {
  __shared__ float As[BK][BM + 4];
  __shared__ float Xs[BK][BN + 4];
  const int b = blockIdx.z;
  const int m0 = blockIdx.y * BM;
  const int n0 = blockIdx.x * BN;
  const int tid = threadIdx.x;
  const int tx = tid % (BN / TN);
  const int ty = tid / (BN / TN);
  const float* Xb = X + (size_t)b * K * N;
  float acc[TM][TN];
#pragma unroll
  for (int i = 0; i < TM; i++)
#pragma unroll
    for (int j = 0; j < TN; j++) acc[i][j] = 0.f;

  for (int k0 = 0; k0 < K; k0 += BK) {
    for (int i = tid; i < BM * BK; i += 256) {
      int r = i / BK, c = i % BK;
      As[c][r] = W[(size_t)(m0 + r) * K + k0 + c];
    }
    for (int i = tid; i < BK * BN; i += 256) {
      int r = i / BN, c = i % BN;
      float x = Xb[(size_t)(k0 + r) * N + n0 + c];
      if (BNRELU) x = fmaxf(fmaf(x, bnscale[k0 + r], bnshift[k0 + r]), 0.f);
      Xs[r][c] = x;
    }
    __syncthreads();
#pragma unroll 4
    for (int kk = 0; kk < BK; kk++) {
      float ra[TM], rb[TN];
#pragma unroll
      for (int i = 0; i < TM; i++) ra[i] = As[kk][ty * TM + i];
#pragma unroll
      for (int j = 0; j < TN; j++) rb[j] = Xs[kk][tx * TN + j];
#pragma unroll
      for (int i = 0; i < TM; i++)
#pragma unroll
        for (int j = 0; j < TN; j++) acc[i][j] = fmaf(ra[i], rb[j], acc[i][j]);
    }
    __syncthreads();
  }
#pragma unroll
  for (int i = 0; i < TM; i++) {
    float bm = bias[m0 + ty * TM + i];
#pragma unroll
    for (int j = 0; j < TN; j++)
      Y[((size_t)b * M + m0 + ty * TM + i) * N + n0 + tx * TN + j] = acc[i][j] + bm;
  }
}

// ---------------- launch ----------------
extern "C" void kernel_launch(void* const* d_in, const int* in_sizes, int n_in,
                              void* d_out, int out_size, void* d_ws, size_t ws_size,
                              hipStream_t stream) {
  const float* feat = (const float*)d_in[0];
  const float* cw1 = (const float*)d_in[1];  const float* cb1 = (const float*)d_in[2];
  const float* cg1 = (const float*)d_in[3];  const float* ct1 = (const float*)d_in[4];
  const float* cw2 = (const float*)d_in[5];  const float* cb2 = (const float*)d_in[6];
  const float* cg2 = (const float*)d_in[7];  const float* ct2 = (const float*)d_in[8];
  const float* cw3 = (const float*)d_in[9];  const float* cb3 = (const float*)d_in[10];
  const float* pw1 = (const float*)d_in[11]; const float* pb1 = (const float*)d_in[12];
  const float* pg1 = (const float*)d_in[13]; const float* pt1 = (const float*)d_in[14];
  const float* pw2 = (const float*)d_in[15]; const float* pb2 = (const float*)d_in[16];
  const float* pg2 = (const float*)d_in[17]; const float* pt2 = (const float*)d_in[18];
  const float* pw3 = (const float*)d_in[19]; const float* pb3 = (const float*)d_in[20];
  const float* mw1 = (const float*)d_in[21]; const float* mb1 = (const float*)d_in[22];
  const float* mg1 = (const float*)d_in[23]; const float* mt1 = (const float*)d_in[24];
  const float* mw2 = (const float*)d_in[25]; const float* mb2 = (const float*)d_in[26];
  const float* mg2 = (const float*)d_in[27]; const float* mt2 = (const float*)d_in[28];
  const float* mw3 = (const float*)d_in[29]; const float* mb3 = (const float*)d_in[30];
  float* out = (float*)d_out;

  // ---- workspace layout: post-GEMM2 buffers alias Y1 ----
  char* p = (char*)d_ws;
  size_t off = 0;
  auto alloc = [&](size_t bytes) { char* r = p + off; off = (off + bytes + 255) & ~(size_t)255; return r; };
  float* Y1 = (float*)alloc(67108864);   // [8][512][4096] f32
  float* Y2 = (float*)alloc(67108864);
  u16* W1H = (u16*)alloc(1048576); u16* W1M = (u16*)alloc(1048576); u16* W1L = (u16*)alloc(1048576);
  u16* W2H = (u16*)alloc(524288);  u16* W2M = (u16*)alloc(524288);  u16* W2L = (u16*)alloc(524288);
  u16* W3H = (u16*)alloc(32768);   u16* W3M = (u16*)alloc(32768);   u16* W3L = (u16*)alloc(32768);
  float* SC1  = (float*)alloc(2048); float* SH1 = (float*)alloc(2048);
  float* SC2  = (float*)alloc(2048); float* SH2 = (float*)alloc(2048);
  float* PSC1 = (float*)alloc(2048); float* PSH1 = (float*)alloc(2048);
  float* PSC2 = (float*)alloc(2048); float* PSH2 = (float*)alloc(2048);
  // ---- sub-arena inside Y1's region: first written AFTER GEMM2 completes ----
  char* q = (char*)Y1;
  size_t qoff = 0;
  auto qalloc = [&](size_t bytes) { char* r = q + qoff; qoff = (qoff + bytes + 255) & ~(size_t)255; return r; };
  float* LSC  = (float*)qalloc(4194304);  // [8][32][4096], written by GEMM3
  float* SCRB = (float*)qalloc(4194304);  // score
  float* LSE  = (float*)qalloc(131072);
  float* GBUF = (float*)qalloc(819200);   // 25*8*16*32*2 floats
  float* GMAX = (float*)qalloc(32768);
  float* T1   = (float*)qalloc(524288);
  float* T2   = (float*)qalloc(524288);
  // contiguous memset region: PIRAW | VLAD | COSTD | NFSQ | NMUSQ | BAR
  const size_t MS_BYTES = 1024 + 1048576 + 4194304 + 131072 + 1024 + 256;
  char* MS = qalloc(MS_BYTES);
  float* PIRAW = (float*)MS;
  float* VLAD  = (float*)(MS + 1024);
  float* COSTD = (float*)(MS + 1024 + 1048576);
  float* NFSQ  = (float*)(MS + 1024 + 1048576 + 4194304);
  float* NMUSQ = (float*)(MS + 1024 + 1048576 + 4194304 + 131072);
  unsigned* BAR = (unsigned*)(MS + 1024 + 1048576 + 4194304 + 131072 + 1024);

  hipMemsetAsync(d_out, 0, sizeof(float), stream);

  float logp = logf(1.0f / NP + 1e-8f);
  float logq = logf(1.0f / KC + 1e-8f);
  dim3 blk(256);

  // weight permute + 3-split (all three sets, one launch)
  convW3_all<<<dim3(4, 32, 3), blk, 0, stream>>>(
      cw1, W1H, W1M, W1L, cw2, W2H, W2M, W2L, cw3, W3H, W3M, W3L);

  // score head: bf16x3 MFMA (f32-equivalent), reg-prefetch pipelined
  gemm_mfma3<128, 4, 4, 4, 2, false><<<dim3(128, 1, 8), blk, 0, stream>>>(
      W1H, W1M, W1L, cb1, feat, nullptr, nullptr, Y1, 1024, 512);
  bnstats<<<dim3(512), blk, 0, stream>>>(Y1, cg1, ct1, SC1, SH1, 512, NP);
  gemm_mfma3<128, 4, 4, 4, 2, true><<<dim3(128, 1, 8), blk, 0, stream>>>(
      W2H, W2M, W2L, cb2, Y1, SC1, SH1, Y2, 512, 512);
  bnstats<<<dim3(512), blk, 0, stream>>>(Y2, cg2, ct2, SC2, SH2, 512, NP);
  // Y1 is now dead -> zero the aliased accumulation buffers inside it
  hipMemsetAsync(MS, 0, MS_BYTES, stream);
  gemm_mfma3<32, 1, 2, 2, 1, true><<<dim3(32, 1, 8), blk, 0, stream>>>(
      W3H, W3M, W3L, cb3, Y2, SC2, SH2, LSC, 512, 32);

  // softmax + pi + lse
  softmax_pi<<<dim3(BB * NP / 256), blk, 0, stream>>>(LSC, SCRB, LSE, PIRAW);

  // vlad (+ fused ||mu||^2)
  vlad_accum<<<dim3(8, DD / 128, BB), blk, 0, stream>>>(feat, SCRB, VLAD);
  vlad_fin<<<dim3(BB * DD / 256), blk, 0, stream>>>(VLAD, PIRAW, GMAX, NMUSQ);

  // cost dots (+ fused ||f||^2)
  cost_accum<<<dim3(4, NP / 128, BB), blk, 0, stream>>>(feat, VLAD, COSTD, NFSQ);

  // fused sinkhorn: normalize + 25 iterations + loss in ONE launch
  sinkhorn_all<<<dim3(NBLK_SINK), blk, 0, stream>>>(
      COSTD, NFSQ, NMUSQ, GBUF, LSC, LSE, out, BAR, logp, logq);

  // fused predictor MLP (one block, activations in LDS)
  mlp_fused<<<dim3(1), dim3(1024), 0, stream>>>(
      mw1, mb1, mg1, mt1, mw2, mb2, mg2, mt2, mw3, mb3,
      GMAX, out + 1 + BB * PP * KC);

  // projector conv head on vlad (N=32, f32)
  gemm_conv<64, 32, 16, 4, 2, false><<<dim3(1, HH / 64, BB), blk, 0, stream>>>(pw1, pb1, VLAD, T1, nullptr, nullptr, HH, DD, KC);
  bnstats<<<dim3(512), blk, 0, stream>>>(T1, pg1, pt1, PSC1, PSH1, HH, KC);
  gemm_conv<64, 32, 16, 4, 2, true><<<dim3(1, HH / 64, BB), blk, 0, stream>>>(pw2, pb2, T1, T2, PSC1, PSH1, HH, HH, KC);
  bnstats<<<dim3(512), blk, 0, stream>>>(T2, pg2, pt2, PSC2, PSH2, HH, KC);
  gemm_conv<64, 32, 16, 4, 2, true><<<dim3(1, PP / 64, BB), blk, 0, stream>>>(pw3, pb3, T2, out + 1, PSC2, PSH2, PP, HH, KC);
}

// Round 4
// 1521.387 us; speedup vs baseline: 1.6561x; 1.6561x over previous
//
#include <hip/hip_runtime.h>
#include <cmath>

#define BB 8
#define DD 1024
#define NP 4096
#define KC 32
#define HH 512
#define PP 128
#define NJB 16          // sinkhorn blocks per batch
#define BN_EPS 1e-5f

typedef unsigned short u16;
typedef short s16x8 __attribute__((ext_vector_type(8)));
typedef float f32x4 __attribute__((ext_vector_type(4)));

// ---------------- wave helpers ----------------
__device__ __forceinline__ float waveReduceSum(float v) {
#pragma unroll
  for (int o = 32; o > 0; o >>= 1) v += __shfl_down(v, o, 64);
  return v;
}

// ---------------- device-scope group barrier (blocks of one batch b) ------
// cnt and gen live 64B apart so arrivals (cnt) don't thrash the pollers (gen).
__device__ __forceinline__ void groupBar(unsigned* cnt, unsigned* gen, unsigned nblk) {
  __threadfence();
  __syncthreads();
  if (threadIdx.x == 0) {
    unsigned g = atomicAdd(gen, 0u);           // device-scope read
    if (atomicAdd(cnt, 1u) == nblk - 1u) {
      atomicExch(cnt, 0u);
      __threadfence();
      atomicAdd(gen, 1u);
    } else {
      while (atomicAdd(gen, 0u) == g) __builtin_amdgcn_s_sleep(8);
    }
  }
  __syncthreads();
  __threadfence();
}

// ---------------- bf16 3-way split: y = h + m + l + O(2^-24 |y|) ----------
__device__ __forceinline__ void split3(float y, short& h, short& m, short& l) {
  unsigned uy = __float_as_uint(y);
  h = (short)(uy >> 16);
  float r1 = y - __uint_as_float(uy & 0xFFFF0000u);
  unsigned um = __float_as_uint(r1);
  m = (short)(um >> 16);
  float r2 = r1 - __uint_as_float(um & 0xFFFF0000u);
  l = (short)(__float_as_uint(r2) >> 16);
}

// ---------------- W pre-permute + 3-split, all three weight sets in one launch
__global__ __launch_bounds__(256) void convW3_all(
    const float* __restrict__ W1, u16* __restrict__ h1, u16* __restrict__ m1, u16* __restrict__ l1,
    const float* __restrict__ W2, u16* __restrict__ h2, u16* __restrict__ m2, u16* __restrict__ l2,
    const float* __restrict__ W3, u16* __restrict__ h3, u16* __restrict__ m3, u16* __restrict__ l3) {
  int z = blockIdx.z;
  const float* W; u16 *hb, *mb, *lb; int K, BM, MTt, KCH;
  if (z == 0)      { W = W1; hb = h1; mb = m1; lb = l1; K = 1024; BM = 128; MTt = 4; KCH = 32; }
  else if (z == 1) { W = W2; hb = h2; mb = m2; lb = l2; K = 512;  BM = 128; MTt = 4; KCH = 16; }
  else             { W = W3; hb = h3; mb = m3; lb = l3; K = 512;  BM = 32;  MTt = 1; KCH = 16; }
  int mt = blockIdx.x, kc = blockIdx.y;
  if (mt >= MTt || kc >= KCH) return;
  const int AU = BM * 4;
  for (int u = threadIdx.x; u < AU; u += 256) {
    int q = u / BM, m = u % BM;
    const float* wp = W + (size_t)(mt * BM + m) * K + kc * 32 + q * 8;
    s16x8 hv, mv, lv;
#pragma unroll
    for (int j = 0; j < 8; j++) {
      short h, mm, l; split3(wp[j], h, mm, l);
      hv[j] = h; mv[j] = mm; lv[j] = l;
    }
    size_t ob = ((size_t)(mt * KCH + kc)) * (size_t)(BM * 32) + (size_t)u * 8;
    *(s16x8*)(hb + ob) = hv;
    *(s16x8*)(mb + ob) = mv;
    *(s16x8*)(lb + ob) = lv;
  }
}

// ---------------- bf16x3 MFMA GEMM (f32-equivalent), reg-prefetch pipelined
template<int BM, int MBLK, int MT, int NT, int WM, bool BNRELU>
__global__ __launch_bounds__(256) void gemm_mfma3(
    const u16* __restrict__ wh, const u16* __restrict__ wmid, const u16* __restrict__ wl,
    const float* __restrict__ bias, const float* __restrict__ X,
    const float* __restrict__ bnsc, const float* __restrict__ bnsh,
    float* __restrict__ Y, int K, int M) {
  __shared__ s16x8 AhS[BM * 4], AmS[BM * 4], AlS[BM * 4];
  __shared__ s16x8 BhS[512], BmS[512], BlS[512];
  const int KCH = K / 32;
  const int tid = threadIdx.x;
  const int bz = blockIdx.z;
  int bid = blockIdx.x;
  int xs = bid & 7, rr = bid >> 3;
  int m_idx = rr % MBLK;
  int n_idx = xs + 8 * (rr / MBLK);

  const int w = tid >> 6, l = tid & 63, q = l >> 4, col = l & 15;
  const int wm = (WM == 1) ? 0 : (w >> 1);
  const int wn = (WM == 1) ? w : (w & 1);
  constexpr int NA = (BM * 4 + 255) / 256;

  f32x4 acc[MT][NT];
#pragma unroll
  for (int i = 0; i < MT; i++)
#pragma unroll
    for (int j = 0; j < NT; j++) { acc[i][j][0] = 0.f; acc[i][j][1] = 0.f; acc[i][j][2] = 0.f; acc[i][j][3] = 0.f; }

  const short* Ah = (const short*)AhS;
  const short* Am = (const short*)AmS;
  const short* Al = (const short*)AlS;
  const short* Bh = (const short*)BhS;
  const short* Bm = (const short*)BmS;
  const short* Bl = (const short*)BlS;

  const float* Xb = X + (size_t)bz * (size_t)K * NP + (size_t)n_idx * 128;
  const size_t abase = (size_t)m_idx * KCH * (size_t)(BM * 32);

  s16x8 rAh[NA], rAm[NA], rAl[NA];
  float rB[2][8];

  {
    const s16x8* awh = (const s16x8*)(wh + abase);
    const s16x8* awm = (const s16x8*)(wmid + abase);
    const s16x8* awl = (const s16x8*)(wl + abase);
#pragma unroll
    for (int t = 0; t < NA; t++) {
      int u = tid + t * 256;
      if (u < BM * 4) { rAh[t] = awh[u]; rAm[t] = awm[u]; rAl[t] = awl[u]; }
    }
#pragma unroll
    for (int t = 0; t < 2; t++) {
      int u = tid + t * 256;
      int qq = u >> 7, n = u & 127;
      const float* fp = Xb + (size_t)(qq * 8) * NP + n;
#pragma unroll
      for (int j = 0; j < 8; j++) {
        float y = fp[(size_t)j * NP];
        if (BNRELU) y = fmaxf(fmaf(y, bnsc[qq * 8 + j], bnsh[qq * 8 + j]), 0.f);
        rB[t][j] = y;
      }
    }
  }

  for (int kc = 0; kc < KCH; kc++) {
#pragma unroll
    for (int t = 0; t < NA; t++) {
      int u = tid + t * 256;
      if (u < BM * 4) { AhS[u] = rAh[t]; AmS[u] = rAm[t]; AlS[u] = rAl[t]; }
    }
#pragma unroll
    for (int t = 0; t < 2; t++) {
      int u = tid + t * 256;
      s16x8 hv, mv, lv;
#pragma unroll
      for (int j = 0; j < 8; j++) {
        short h, mm, ll; split3(rB[t][j], h, mm, ll);
        hv[j] = h; mv[j] = mm; lv[j] = ll;
      }
      BhS[u] = hv; BmS[u] = mv; BlS[u] = lv;
    }
    __syncthreads();

    if (kc + 1 < KCH) {
      size_t ab = abase + (size_t)(kc + 1) * (size_t)(BM * 32);
      const s16x8* awh = (const s16x8*)(wh + ab);
      const s16x8* awm = (const s16x8*)(wmid + ab);
      const s16x8* awl = (const s16x8*)(wl + ab);
#pragma unroll
      for (int t = 0; t < NA; t++) {
        int u = tid + t * 256;
        if (u < BM * 4) { rAh[t] = awh[u]; rAm[t] = awm[u]; rAl[t] = awl[u]; }
      }
      const int kp = (kc + 1) * 32;
#pragma unroll
      for (int t = 0; t < 2; t++) {
        int u = tid + t * 256;
        int qq = u >> 7, n = u & 127;
        const float* fp = Xb + (size_t)(kp + qq * 8) * NP + n;
#pragma unroll
        for (int j = 0; j < 8; j++) {
          float y = fp[(size_t)j * NP];
          if (BNRELU) y = fmaxf(fmaf(y, bnsc[kp + qq * 8 + j], bnsh[kp + qq * 8 + j]), 0.f);
          rB[t][j] = y;
        }
      }
    }

    s16x8 ah[MT], am[MT], al[MT];
#pragma unroll
    for (int i = 0; i < MT; i++) {
      int off = (q * BM + wm * (MT * 16) + i * 16 + col) * 8;
      ah[i] = *(const s16x8*)(Ah + off);
      am[i] = *(const s16x8*)(Am + off);
      al[i] = *(const s16x8*)(Al + off);
    }
    __builtin_amdgcn_s_setprio(1);
#pragma unroll
    for (int j = 0; j < NT; j++) {
      int offb = (q * 128 + wn * (NT * 16) + j * 16 + col) * 8;
      s16x8 bh = *(const s16x8*)(Bh + offb);
      s16x8 bm = *(const s16x8*)(Bm + offb);
      s16x8 bl = *(const s16x8*)(Bl + offb);
#pragma unroll
      for (int i = 0; i < MT; i++) {
        acc[i][j] = __builtin_amdgcn_mfma_f32_16x16x32_bf16(ah[i], bh, acc[i][j], 0, 0, 0);
        acc[i][j] = __builtin_amdgcn_mfma_f32_16x16x32_bf16(ah[i], bm, acc[i][j], 0, 0, 0);
        acc[i][j] = __builtin_amdgcn_mfma_f32_16x16x32_bf16(am[i], bh, acc[i][j], 0, 0, 0);
        acc[i][j] = __builtin_amdgcn_mfma_f32_16x16x32_bf16(ah[i], bl, acc[i][j], 0, 0, 0);
        acc[i][j] = __builtin_amdgcn_mfma_f32_16x16x32_bf16(am[i], bm, acc[i][j], 0, 0, 0);
        acc[i][j] = __builtin_amdgcn_mfma_f32_16x16x32_bf16(al[i], bh, acc[i][j], 0, 0, 0);
      }
    }
    __builtin_amdgcn_s_setprio(0);
    __syncthreads();
  }
#pragma unroll
  for (int i = 0; i < MT; i++) {
#pragma unroll
    for (int r = 0; r < 4; r++) {
      int m = m_idx * BM + wm * (MT * 16) + i * 16 + q * 4 + r;
      float bv = bias[m];
#pragma unroll
      for (int j = 0; j < NT; j++) {
        int n = n_idx * 128 + wn * (NT * 16) + j * 16 + col;
        Y[((size_t)bz * M + m) * 4096 + n] = acc[i][j][r] + bv;
      }
    }
  }
}

// ---------------- BN (training, batch stats over B and N) per channel
__global__ __launch_bounds__(256) void bnstats(
    const float* __restrict__ Y, const float* __restrict__ g, const float* __restrict__ beta,
    float* __restrict__ scale, float* __restrict__ shift, int C, int N) {
  int c = blockIdx.x;
  float s = 0.f, sq = 0.f;
  for (int b = 0; b < BB; b++) {
    const float* p = Y + ((size_t)b * C + c) * N;
    for (int n = threadIdx.x; n < N; n += 256) { float v = p[n]; s += v; sq += v * v; }
  }
  __shared__ float shs[4], shq[4];
  int lane = threadIdx.x & 63, wid = threadIdx.x >> 6;
  s = waveReduceSum(s); sq = waveReduceSum(sq);
  if (lane == 0) { shs[wid] = s; shq[wid] = sq; }
  __syncthreads();
  if (threadIdx.x == 0) {
    float S = shs[0] + shs[1] + shs[2] + shs[3];
    float Q = shq[0] + shq[1] + shq[2] + shq[3];
    float cnt = (float)(BB * N);
    float mean = S / cnt;
    float var = Q / cnt - mean * mean;
    float sc = g[c] / sqrtf(var + BN_EPS);
    scale[c] = sc; shift[c] = beta[c] - mean * sc;
  }
}

// ---------------- softmax over K (axis=1), write score, lse per (b,n), pi partial sums
__global__ __launch_bounds__(256) void softmax_pi(
    const float* __restrict__ LSm, float* __restrict__ score,
    float* __restrict__ lseArr, float* __restrict__ pi_raw) {
  int gidx = blockIdx.x * 256 + threadIdx.x;
  int b = gidx / NP, n = gidx % NP;
  const float* p = LSm + (size_t)b * KC * NP + n;
  float v[KC];
  float m = -1e30f;
#pragma unroll
  for (int k = 0; k < KC; k++) { v[k] = p[(size_t)k * NP]; m = fmaxf(m, v[k]); }
  float s = 0.f;
#pragma unroll
  for (int k = 0; k < KC; k++) { v[k] = expf(v[k] - m); s += v[k]; }
  float inv = 1.f / s;
  float* qq = score + (size_t)b * KC * NP + n;
#pragma unroll
  for (int k = 0; k < KC; k++) { v[k] *= inv; qq[(size_t)k * NP] = v[k]; }
  lseArr[gidx] = m + logf(s);
  __shared__ float ps[KC];
  if (threadIdx.x < KC) ps[threadIdx.x] = 0.f;
  __syncthreads();
  int lane = threadIdx.x & 63;
#pragma unroll
  for (int k = 0; k < KC; k++) {
    float w = waveReduceSum(v[k]);
    if (lane == 0) atomicAdd(&ps[k], w);
  }
  __syncthreads();
  if (threadIdx.x < KC) atomicAdd(&pi_raw[b * KC + threadIdx.x], ps[threadIdx.x]);
}

// ---------------- vlad accumulation (split over n, atomic)
__global__ __launch_bounds__(256) void vlad_accum(
    const float* __restrict__ feat, const float* __restrict__ score, float* __restrict__ vlad) {
  const int SPLIT_LEN = NP / 8;
  int sp = blockIdx.x, dt = blockIdx.y, b = blockIdx.z;
  int d0 = dt * 128;
  int n_start = sp * SPLIT_LEN;
  __shared__ float As[32][132];
  __shared__ float Bs[32][36];
  int tid = threadIdx.x;
  int tx = tid % 16;
  int ty = tid / 16;
  float acc[8][2] = {};
  const float* fb = feat + (size_t)b * DD * NP;
  const float* sb = score + (size_t)b * KC * NP;
  for (int nc = 0; nc < SPLIT_LEN; nc += 32) {
    int n0 = n_start + nc;
    for (int i = tid; i < 128 * 32; i += 256) {
      int r = i >> 5, c = i & 31;
      As[c][r] = fb[(size_t)(d0 + r) * NP + n0 + c];
    }
    for (int i = tid; i < 32 * 32; i += 256) {
      int r = i >> 5, c = i & 31;
      Bs[c][r] = sb[(size_t)r * NP + n0 + c];
    }
    __syncthreads();
#pragma unroll 4
    for (int kk = 0; kk < 32; kk++) {
      float ra[8], rb[2];
#pragma unroll
      for (int i = 0; i < 8; i++) ra[i] = As[kk][ty * 8 + i];
      rb[0] = Bs[kk][tx * 2]; rb[1] = Bs[kk][tx * 2 + 1];
#pragma unroll
      for (int i = 0; i < 8; i++) { acc[i][0] = fmaf(ra[i], rb[0], acc[i][0]); acc[i][1] = fmaf(ra[i], rb[1], acc[i][1]); }
    }
    __syncthreads();
  }
#pragma unroll
  for (int i = 0; i < 8; i++)
#pragma unroll
    for (int j = 0; j < 2; j++)
      atomicAdd(&vlad[((size_t)b * DD + d0 + ty * 8 + i) * KC + tx * 2 + j], acc[i][j]);
}

// ---------------- vlad finalize + gmax + fused ||mu_k||^2 partials
__global__ __launch_bounds__(256) void vlad_fin(
    float* __restrict__ vlad, const float* __restrict__ pi_raw, float* __restrict__ gmax,
    float* __restrict__ nmusq) {
  int idx = blockIdx.x * 256 + threadIdx.x;
  int b = idx / DD;
  float* p = vlad + (size_t)idx * KC;
  const float* pr = pi_raw + b * KC;
  float gm = -1e30f;
  __shared__ float wk[4][KC];
  int lane = threadIdx.x & 63, wid = threadIdx.x >> 6;
#pragma unroll
  for (int k = 0; k < KC; k++) {
    float v = p[k] / fmaxf(pr[k], 1e-4f);
    p[k] = v;
    gm = fmaxf(gm, v);
    float s2 = waveReduceSum(v * v);
    if (lane == 0) wk[wid][k] = s2;
  }
  gmax[idx] = gm;
  __syncthreads();
  if (threadIdx.x < KC) {
    float t = wk[0][threadIdx.x] + wk[1][threadIdx.x] + wk[2][threadIdx.x] + wk[3][threadIdx.x];
    atomicAdd(&nmusq[b * KC + threadIdx.x], t);
  }
}

// ---------------- cost dot accumulation (split over d, atomic) + fused ||f_n||^2
__global__ __launch_bounds__(256) void cost_accum(
    const float* __restrict__ feat, const float* __restrict__ vlad, float* __restrict__ costd,
    float* __restrict__ nfsq) {
  int sp = blockIdx.x, nt = blockIdx.y, b = blockIdx.z;
  int n0 = nt * 128;
  int d_start = sp * (DD / 4);
  __shared__ float As[32][132];
  __shared__ float Bs[32][36];
  __shared__ float nfs[128];
  int tid = threadIdx.x;
  int tx = tid % 16;
  int ty = tid / 16;
  float acc[8][2] = {};
  float sq = 0.f;
  const float* fb = feat + (size_t)b * DD * NP;
  const float* vb = vlad + (size_t)b * DD * KC;
  for (int dc = 0; dc < DD / 4; dc += 32) {
    int dd0 = d_start + dc;
    for (int i = tid; i < 32 * 128; i += 256) {
      int r = i >> 7, c = i & 127;
      float v = fb[(size_t)(dd0 + r) * NP + n0 + c];
      As[r][c] = v;
      sq = fmaf(v, v, sq);
    }
    for (int i = tid; i < 32 * 32; i += 256) {
      int r = i >> 5, c = i & 31;
      Bs[r][c] = vb[(size_t)(dd0 + r) * KC + c];
    }
    __syncthreads();
#pragma unroll 4
    for (int kk = 0; kk < 32; kk++) {
      float ra[8], rb[2];
#pragma unroll
      for (int i = 0; i < 8; i++) ra[i] = As[kk][ty * 8 + i];
      rb[0] = Bs[kk][tx * 2]; rb[1] = Bs[kk][tx * 2 + 1];
#pragma unroll
      for (int i = 0; i < 8; i++) { acc[i][0] = fmaf(ra[i], rb[0], acc[i][0]); acc[i][1] = fmaf(ra[i], rb[1], acc[i][1]); }
    }
    __syncthreads();
  }
#pragma unroll
  for (int i = 0; i < 8; i++)
#pragma unroll
    for (int j = 0; j < 2; j++)
      atomicAdd(&costd[((size_t)b * NP + n0 + ty * 8 + i) * KC + tx * 2 + j], acc[i][j]);
  if (tid < 128) nfs[tid] = 0.f;
  __syncthreads();
  atomicAdd(&nfs[tid & 127], sq);
  __syncthreads();
  if (tid < 128) atomicAdd(&nfsq[(size_t)b * NP + n0 + tid], sq = nfs[tid]);
}

// ---------------- fused sinkhorn: cost_fin + 25 iterations + loss, ONE launch
// 128 blocks (16 per b, 256 rows each). Each thread keeps its normalized cost
// row (32 f32) in registers for all 25 iterations. Cross-block v-reduction via
// G partials; PER-B 16-block barrier (v-update only needs same-b partials).
__global__ __launch_bounds__(256) void sinkhorn_all(
    const float* __restrict__ costd, const float* __restrict__ nfsq,
    const float* __restrict__ nmusq, float* __restrict__ G,
    const float* __restrict__ LSm, const float* __restrict__ lseArr,
    float* __restrict__ out0, unsigned* __restrict__ bar,
    float logp, float logq) {
  const float EPS = 1e-3f, IEPS = 1000.f;
  int b = blockIdx.x / NJB, j = blockIdx.x % NJB;
  int tid = threadIdx.x;
  int n = j * 256 + tid;
  unsigned* mybar = bar + (size_t)b * 32;      // 128B-spaced per-b barrier; gen at +16 (64B)
  __shared__ float vsh[KC];
  __shared__ float nmS[KC];
  __shared__ float vals[256][33];   // (u - c)/eps staging, +1 pad
  __shared__ float red[KC][9];      // 8 segment partials per k
  __shared__ float bmS[KC];
  __shared__ float redL[4];

  if (tid < KC) nmS[tid] = fmaxf(sqrtf(nmusq[b * KC + tid]), 1e-12f);
  __syncthreads();

  // load + normalize this thread's cost row into registers (cost_fin folded)
  float c[KC];
  {
    const float* dp = costd + ((size_t)b * NP + n) * KC;
    float nf = fmaxf(sqrtf(nfsq[(size_t)b * NP + n]), 1e-12f);
#pragma unroll
    for (int k = 0; k < KC; k++) c[k] = 2.f - 2.f * dp[k] / (nf * nmS[k]);
  }

  const int kk = tid & 31, seg = tid >> 5;   // reduction mapping: 8 segs x 32 rows
  const int r0 = seg * 32;
  float u = 0.f;

  for (int t = 1; t <= 25; t++) {
    if (tid < KC) {
      float v = 0.f;
      if (t > 1) {
        const float* Gp = G + (((size_t)(t - 2) * BB + b) * NJB) * KC * 2;
        float m = -1e30f;
        for (int jj = 0; jj < NJB; jj++) m = fmaxf(m, Gp[(jj * KC + tid) * 2]);
        float s = 0.f;
        for (int jj = 0; jj < NJB; jj++) s += Gp[(jj * KC + tid) * 2 + 1] * expf(Gp[(jj * KC + tid) * 2] - m);
        v = EPS * logq - EPS * (m + logf(s));
      }
      vsh[tid] = v;
    }
    __syncthreads();
    // u update for this thread's row (all from regs/LDS-broadcast)
    float m = -1e30f;
#pragma unroll
    for (int k = 0; k < KC; k++) m = fmaxf(m, vsh[k] - c[k]);
    float s = 0.f;
#pragma unroll
    for (int k = 0; k < KC; k++) s += expf((vsh[k] - c[k] - m) * IEPS);
    u = EPS * logp - m - EPS * logf(s);
    // stage scaled values for the per-k block reduction
#pragma unroll
    for (int k = 0; k < KC; k++) vals[tid][k] = (u - c[k]) * IEPS;
    __syncthreads();
    // per-k max over this block's 256 rows (8 segments of 32)
    {
      float lm = -1e30f;
      for (int r = 0; r < 32; r++) lm = fmaxf(lm, vals[r0 + r][kk]);
      red[kk][seg] = lm;
    }
    __syncthreads();
    if (tid < KC) {
      float bm = red[tid][0];
      for (int i2 = 1; i2 < 8; i2++) bm = fmaxf(bm, red[tid][i2]);
      bmS[tid] = bm;
    }
    __syncthreads();
    {
      float bm = bmS[kk];
      float ls = 0.f;
      for (int r = 0; r < 32; r++) ls += expf(vals[r0 + r][kk] - bm);
      red[kk][seg] = ls;
    }
    __syncthreads();
    if (tid < KC) {
      float s8 = 0.f;
      for (int i2 = 0; i2 < 8; i2++) s8 += red[tid][i2];
      float* Gp = G + ((((size_t)(t - 1) * BB + b) * NJB + j) * KC + tid) * 2;
      Gp[0] = bmS[tid]; Gp[1] = s8;
    }
    groupBar(mybar, mybar + 16, NJB);
  }

  // ---- loss: u currently holds u25 (computed from v24 in iteration 25)
  __shared__ float v25S[KC];
  if (tid < KC) {
    const float* Gp = G + (((size_t)24 * BB + b) * NJB) * KC * 2;
    float m = -1e30f;
    for (int jj = 0; jj < NJB; jj++) m = fmaxf(m, Gp[(jj * KC + tid) * 2]);
    float s = 0.f;
    for (int jj = 0; jj < NJB; jj++) s += Gp[(jj * KC + tid) * 2 + 1] * expf(Gp[(jj * KC + tid) * 2] - m);
    v25S[tid] = EPS * logq - EPS * (m + logf(s));
  }
  __syncthreads();
  float lsev = lseArr[(size_t)b * NP + n];
  float part = 0.f;
#pragma unroll
  for (int k = 0; k < KC; k++) {
    float gamma = expf((u + v25S[k] - c[k]) * IEPS);
    float logsm = LSm[((size_t)b * KC + k) * NP + n] - lsev;
    part += gamma * logsm;
  }
  part *= (float)NP;
  int lane = tid & 63, wid = tid >> 6;
  part = waveReduceSum(part);
  if (lane == 0) redL[wid] = part;
  __syncthreads();
  if (tid == 0) {
    float tt = redL[0] + redL[1] + redL[2] + redL[3];
    atomicAdd(out0, -tt / (float)(BB * NP));
  }
}

// ---------------- tiled f32 conv1x1 GEMM (projector head, N=32 tiny)
template<int BM, int BN, int BK, int TM, int TN, bool BNRELU>
__global__ __launch_bounds__(256) void gemm_conv(
    const float* __restrict__ W, const float* __restrict__ bias,
    const float* __restrict__ X, float* __restrict__ Y,
    const float* __restrict__ bnscale, const float* __restrict__ bnshift,
    int M, int K, int N) {
  __shared__ float As[BK][BM + 4];
  __shared__ float Xs[BK][BN + 4];
  const int b = blockIdx.z;
  const int m0 = blockIdx.y * BM;
  const int n0 = blockIdx.x * BN;
  const int tid = threadIdx.x;
  const int tx = tid % (BN / TN);
  const int ty = tid / (BN / TN);
  const float* Xb = X + (size_t)b * K * N;
  float acc[TM][TN];
#pragma unroll
  for (int i = 0; i < TM; i++)
#pragma unroll
    for (int j = 0; j < TN; j++) acc[i][j] = 0.f;

  for (int k0 = 0; k0 < K; k0 += BK) {
    for (int i = tid; i < BM * BK; i += 256) {
      int r = i / BK, c = i % BK;
      As[c][r] = W[(size_t)(m0 + r) * K + k0 + c];
    }
    for (int i = tid; i < BK * BN; i += 256) {
      int r = i / BN, c = i % BN;
      float x = Xb[(size_t)(k0 + r) * N + n0 + c];
      if (BNRELU) x = fmaxf(fmaf(x, bnscale[k0 + r], bnshift[k0 + r]), 0.f);
      Xs[r][c] = x;
    }
    __syncthreads();
#pragma unroll 4
    for (int kk = 0; kk < BK; kk++) {
      float ra[TM], rb[TN];
#pragma unroll
      for (int i = 0; i < TM; i++) ra[i] = As[kk][ty * TM + i];
#pragma unroll
      for (int j = 0; j < TN; j++) rb[j] = Xs[kk][tx * TN + j];
#pragma unroll
      for (int i = 0; i < TM; i++)
#pragma unroll
        for (int j = 0; j < TN; j++) acc[i][j] = fmaf(ra[i], rb[j], acc[i][j]);
    }
    __syncthreads();
  }
#pragma unroll
  for (int i = 0; i < TM; i++) {
    float bm = bias[m0 + ty * TM + i];
#pragma unroll
    for (int j = 0; j < TN; j++)
      Y[((size_t)b * M + m0 + ty * TM + i) * N + n0 + tx * TN + j] = acc[i][j] + bm;
  }
}

// ---------------- tiny MLP gemm: one wave per output element
template<bool BNRELU>
__global__ __launch_bounds__(256) void mlp_gemm(
    const float* __restrict__ W, const float* __restrict__ bias,
    const float* __restrict__ in, float* __restrict__ out,
    const float* __restrict__ sc, const float* __restrict__ sh, int M, int K) {
  int gw = (blockIdx.x * 256 + threadIdx.x) >> 6;   // global wave id = output idx
  int lane = threadIdx.x & 63;
  int s = gw / M, jj = gw % M;
  const float4* ip = (const float4*)(in + (size_t)s * K);
  const float4* wp = (const float4*)(W + (size_t)jj * K);
  float acc = 0.f;
  for (int c4 = lane; c4 < (K >> 2); c4 += 64) {
    float4 x = ip[c4];
    float4 w = wp[c4];
    if (BNRELU) {
      int cb = c4 * 4;
      x.x = fmaxf(fmaf(x.x, sc[cb + 0], sh[cb + 0]), 0.f);
      x.y = fmaxf(fmaf(x.y, sc[cb + 1], sh[cb + 1]), 0.f);
      x.z = fmaxf(fmaf(x.z, sc[cb + 2], sh[cb + 2]), 0.f);
      x.w = fmaxf(fmaf(x.w, sc[cb + 3], sh[cb + 3]), 0.f);
    }
    acc += x.x * w.x + x.y * w.y + x.z * w.z + x.w * w.w;
  }
  acc = waveReduceSum(acc);
  if (lane == 0) out[gw] = acc + bias[jj];
}

__global__ __launch_bounds__(256) void mlp_bnstats(
    const float* __restrict__ mat, const float* __restrict__ g, const float* __restrict__ beta,
    float* __restrict__ scale, float* __restrict__ shift, int M) {
  int j = blockIdx.x * 256 + threadIdx.x;
  if (j >= M) return;
  float s = 0.f, sq = 0.f;
  for (int si = 0; si < BB; si++) { float v = mat[si * M + j]; s += v; sq += v * v; }
  float mean = s / (float)BB;
  float var = sq / (float)BB - mean * mean;
  float sc = g[j] / sqrtf(var + BN_EPS);
  scale[j] = sc; shift[j] = beta[j] - mean * sc;
}

// ---------------- launch ----------------
extern "C" void kernel_launch(void* const* d_in, const int* in_sizes, int n_in,
                              void* d_out, int out_size, void* d_ws, size_t ws_size,
                              hipStream_t stream) {
  const float* feat = (const float*)d_in[0];
  const float* cw1 = (const float*)d_in[1];  const float* cb1 = (const float*)d_in[2];
  const float* cg1 = (const float*)d_in[3];  const float* ct1 = (const float*)d_in[4];
  const float* cw2 = (const float*)d_in[5];  const float* cb2 = (const float*)d_in[6];
  const float* cg2 = (const float*)d_in[7];  const float* ct2 = (const float*)d_in[8];
  const float* cw3 = (const float*)d_in[9];  const float* cb3 = (const float*)d_in[10];
  const float* pw1 = (const float*)d_in[11]; const float* pb1 = (const float*)d_in[12];
  const float* pg1 = (const float*)d_in[13]; const float* pt1 = (const float*)d_in[14];
  const float* pw2 = (const float*)d_in[15]; const float* pb2 = (const float*)d_in[16];
  const float* pg2 = (const float*)d_in[17]; const float* pt2 = (const float*)d_in[18];
  const float* pw3 = (const float*)d_in[19]; const float* pb3 = (const float*)d_in[20];
  const float* mw1 = (const float*)d_in[21]; const float* mb1 = (const float*)d_in[22];
  const float* mg1 = (const float*)d_in[23]; const float* mt1 = (const float*)d_in[24];
  const float* mw2 = (const float*)d_in[25]; const float* mb2 = (const float*)d_in[26];
  const float* mg2 = (const float*)d_in[27]; const float* mt2 = (const float*)d_in[28];
  const float* mw3 = (const float*)d_in[29]; const float* mb3 = (const float*)d_in[30];
  float* out = (float*)d_out;

  // ---- workspace layout: post-GEMM2 buffers alias Y1 ----
  char* p = (char*)d_ws;
  size_t off = 0;
  auto alloc = [&](size_t bytes) { char* r = p + off; off = (off + bytes + 255) & ~(size_t)255; return r; };
  float* Y1 = (float*)alloc(67108864);   // [8][512][4096] f32
  float* Y2 = (float*)alloc(67108864);
  u16* W1H = (u16*)alloc(1048576); u16* W1M = (u16*)alloc(1048576); u16* W1L = (u16*)alloc(1048576);
  u16* W2H = (u16*)alloc(524288);  u16* W2M = (u16*)alloc(524288);  u16* W2L = (u16*)alloc(524288);
  u16* W3H = (u16*)alloc(32768);   u16* W3M = (u16*)alloc(32768);   u16* W3L = (u16*)alloc(32768);
  float* SC1  = (float*)alloc(2048); float* SH1 = (float*)alloc(2048);
  float* SC2  = (float*)alloc(2048); float* SH2 = (float*)alloc(2048);
  float* PSC1 = (float*)alloc(2048); float* PSH1 = (float*)alloc(2048);
  float* PSC2 = (float*)alloc(2048); float* PSH2 = (float*)alloc(2048);
  float* MSC1 = (float*)alloc(2048); float* MSH1 = (float*)alloc(2048);
  float* MSC2 = (float*)alloc(2048); float* MSH2 = (float*)alloc(2048);
  // ---- sub-arena inside Y1's region: first written AFTER GEMM2 completes ----
  char* q = (char*)Y1;
  size_t qoff = 0;
  auto qalloc = [&](size_t bytes) { char* r = q + qoff; qoff = (qoff + bytes + 255) & ~(size_t)255; return r; };
  float* LSC  = (float*)qalloc(4194304);  // [8][32][4096], written by GEMM3
  float* SCRB = (float*)qalloc(4194304);  // score
  float* LSE  = (float*)qalloc(131072);
  float* GBUF = (float*)qalloc(819200);   // 25*8*16*32*2 floats
  float* GMAX = (float*)qalloc(32768);
  float* MH1  = (float*)qalloc(16384);
  float* MH2  = (float*)qalloc(16384);
  float* T1   = (float*)qalloc(524288);
  float* T2   = (float*)qalloc(524288);
  // contiguous memset region: PIRAW | VLAD | COSTD | NFSQ | NMUSQ | BAR(1KB)
  const size_t MS_BYTES = 1024 + 1048576 + 4194304 + 131072 + 1024 + 1024;
  char* MS = qalloc(MS_BYTES);
  float* PIRAW = (float*)MS;
  float* VLAD  = (float*)(MS + 1024);
  float* COSTD = (float*)(MS + 1024 + 1048576);
  float* NFSQ  = (float*)(MS + 1024 + 1048576 + 4194304);
  float* NMUSQ = (float*)(MS + 1024 + 1048576 + 4194304 + 131072);
  unsigned* BAR = (unsigned*)(MS + 1024 + 1048576 + 4194304 + 131072 + 1024);

  hipMemsetAsync(d_out, 0, sizeof(float), stream);

  float logp = logf(1.0f / NP + 1e-8f);
  float logq = logf(1.0f / KC + 1e-8f);
  dim3 blk(256);

  // weight permute + 3-split (all three sets, one launch)
  convW3_all<<<dim3(4, 32, 3), blk, 0, stream>>>(
      cw1, W1H, W1M, W1L, cw2, W2H, W2M, W2L, cw3, W3H, W3M, W3L);

  // score head: bf16x3 MFMA (f32-equivalent), reg-prefetch pipelined
  gemm_mfma3<128, 4, 4, 4, 2, false><<<dim3(128, 1, 8), blk, 0, stream>>>(
      W1H, W1M, W1L, cb1, feat, nullptr, nullptr, Y1, 1024, 512);
  bnstats<<<dim3(512), blk, 0, stream>>>(Y1, cg1, ct1, SC1, SH1, 512, NP);
  gemm_mfma3<128, 4, 4, 4, 2, true><<<dim3(128, 1, 8), blk, 0, stream>>>(
      W2H, W2M, W2L, cb2, Y1, SC1, SH1, Y2, 512, 512);
  bnstats<<<dim3(512), blk, 0, stream>>>(Y2, cg2, ct2, SC2, SH2, 512, NP);
  // Y1 is now dead -> zero the aliased accumulation buffers inside it
  hipMemsetAsync(MS, 0, MS_BYTES, stream);
  gemm_mfma3<32, 1, 2, 2, 1, true><<<dim3(32, 1, 8), blk, 0, stream>>>(
      W3H, W3M, W3L, cb3, Y2, SC2, SH2, LSC, 512, 32);

  // softmax + pi + lse
  softmax_pi<<<dim3(BB * NP / 256), blk, 0, stream>>>(LSC, SCRB, LSE, PIRAW);

  // vlad (+ fused ||mu||^2)
  vlad_accum<<<dim3(8, DD / 128, BB), blk, 0, stream>>>(feat, SCRB, VLAD);
  vlad_fin<<<dim3(BB * DD / 256), blk, 0, stream>>>(VLAD, PIRAW, GMAX, NMUSQ);

  // cost dots (+ fused ||f||^2)
  cost_accum<<<dim3(4, NP / 128, BB), blk, 0, stream>>>(feat, VLAD, COSTD, NFSQ);

  // fused sinkhorn: normalize + 25 iterations + loss in ONE launch (per-b barriers)
  sinkhorn_all<<<dim3(BB * NJB), blk, 0, stream>>>(
      COSTD, NFSQ, NMUSQ, GBUF, LSC, LSE, out, BAR, logp, logq);

  // predictor MLP on max-pooled vlad (wave-per-output, multi-block — reverted:
  // single-block fused variant measured 776 us at 0.19% occupancy)
  mlp_gemm<false><<<dim3(BB * HH / 4), blk, 0, stream>>>(mw1, mb1, GMAX, MH1, nullptr, nullptr, HH, DD);
  mlp_bnstats<<<dim3(2), blk, 0, stream>>>(MH1, mg1, mt1, MSC1, MSH1, HH);
  mlp_gemm<true><<<dim3(BB * HH / 4), blk, 0, stream>>>(mw2, mb2, MH1, MH2, MSC1, MSH1, HH, HH);
  mlp_bnstats<<<dim3(2), blk, 0, stream>>>(MH2, mg2, mt2, MSC2, MSH2, HH);
  mlp_gemm<true><<<dim3(BB * PP / 4), blk, 0, stream>>>(mw3, mb3, MH2, out + 1 + BB * PP * KC, MSC2, MSH2, PP, HH);

  // projector conv head on vlad (N=32, f32)
  gemm_conv<64, 32, 16, 4, 2, false><<<dim3(1, HH / 64, BB), blk, 0, stream>>>(pw1, pb1, VLAD, T1, nullptr, nullptr, HH, DD, KC);
  bnstats<<<dim3(512), blk, 0, stream>>>(T1, pg1, pt1, PSC1, PSH1, HH, KC);
  gemm_conv<64, 32, 16, 4, 2, true><<<dim3(1, HH / 64, BB), blk, 0, stream>>>(pw2, pb2, T1, T2, PSC1, PSH1, HH, HH, KC);
  bnstats<<<dim3(512), blk, 0, stream>>>(T2, pg2, pt2, PSC2, PSH2, HH, KC);
  gemm_conv<64, 32, 16, 4, 2, true><<<dim3(1, PP / 64, BB), blk, 0, stream>>>(pw3, pb3, T2, out + 1, PSC2, PSH2, PP, HH, KC);
}

// Round 5
// 1226.609 us; speedup vs baseline: 2.0541x; 1.2403x over previous
//
#include <hip/hip_runtime.h>
#include <cmath>

#define BB 8
#define DD 1024
#define NP 4096
#define KC 32
#define HH 512
#define PP 128
#define NJB 16          // sinkhorn blocks per batch
#define BN_EPS 1e-5f

typedef unsigned short u16;
typedef short s16x8 __attribute__((ext_vector_type(8)));
typedef float f32x4 __attribute__((ext_vector_type(4)));

// ---------------- wave helpers ----------------
__device__ __forceinline__ float waveReduceSum(float v) {
#pragma unroll
  for (int o = 32; o > 0; o >>= 1) v += __shfl_down(v, o, 64);
  return v;
}

// ---------------- bf16 3-way split: y = h + m + l + O(2^-24 |y|) ----------
__device__ __forceinline__ void split3(float y, short& h, short& m, short& l) {
  unsigned uy = __float_as_uint(y);
  h = (short)(uy >> 16);
  float r1 = y - __uint_as_float(uy & 0xFFFF0000u);
  unsigned um = __float_as_uint(r1);
  m = (short)(um >> 16);
  float r2 = r1 - __uint_as_float(um & 0xFFFF0000u);
  l = (short)(__float_as_uint(r2) >> 16);
}

// ---------------- W pre-permute + 3-split, all three weight sets in one launch
__global__ __launch_bounds__(256) void convW3_all(
    const float* __restrict__ W1, u16* __restrict__ h1, u16* __restrict__ m1, u16* __restrict__ l1,
    const float* __restrict__ W2, u16* __restrict__ h2, u16* __restrict__ m2, u16* __restrict__ l2,
    const float* __restrict__ W3, u16* __restrict__ h3, u16* __restrict__ m3, u16* __restrict__ l3) {
  int z = blockIdx.z;
  const float* W; u16 *hb, *mb, *lb; int K, BM, MTt, KCH;
  if (z == 0)      { W = W1; hb = h1; mb = m1; lb = l1; K = 1024; BM = 128; MTt = 4; KCH = 32; }
  else if (z == 1) { W = W2; hb = h2; mb = m2; lb = l2; K = 512;  BM = 128; MTt = 4; KCH = 16; }
  else             { W = W3; hb = h3; mb = m3; lb = l3; K = 512;  BM = 32;  MTt = 1; KCH = 16; }
  int mt = blockIdx.x, kc = blockIdx.y;
  if (mt >= MTt || kc >= KCH) return;
  const int AU = BM * 4;
  for (int u = threadIdx.x; u < AU; u += 256) {
    int q = u / BM, m = u % BM;
    const float* wp = W + (size_t)(mt * BM + m) * K + kc * 32 + q * 8;
    s16x8 hv, mv, lv;
#pragma unroll
    for (int j = 0; j < 8; j++) {
      short h, mm, l; split3(wp[j], h, mm, l);
      hv[j] = h; mv[j] = mm; lv[j] = l;
    }
    size_t ob = ((size_t)(mt * KCH + kc)) * (size_t)(BM * 32) + (size_t)u * 8;
    *(s16x8*)(hb + ob) = hv;
    *(s16x8*)(mb + ob) = mv;
    *(s16x8*)(lb + ob) = lv;
  }
}

// ---------------- bf16x3 MFMA GEMM (f32-equivalent), reg-prefetch pipelined
template<int BM, int MBLK, int MT, int NT, int WM, bool BNRELU>
__global__ __launch_bounds__(256) void gemm_mfma3(
    const u16* __restrict__ wh, const u16* __restrict__ wmid, const u16* __restrict__ wl,
    const float* __restrict__ bias, const float* __restrict__ X,
    const float* __restrict__ bnsc, const float* __restrict__ bnsh,
    float* __restrict__ Y, int K, int M) {
  __shared__ s16x8 AhS[BM * 4], AmS[BM * 4], AlS[BM * 4];
  __shared__ s16x8 BhS[512], BmS[512], BlS[512];
  const int KCH = K / 32;
  const int tid = threadIdx.x;
  const int bz = blockIdx.z;
  int bid = blockIdx.x;
  int xs = bid & 7, rr = bid >> 3;
  int m_idx = rr % MBLK;
  int n_idx = xs + 8 * (rr / MBLK);

  const int w = tid >> 6, l = tid & 63, q = l >> 4, col = l & 15;
  const int wm = (WM == 1) ? 0 : (w >> 1);
  const int wn = (WM == 1) ? w : (w & 1);
  constexpr int NA = (BM * 4 + 255) / 256;

  f32x4 acc[MT][NT];
#pragma unroll
  for (int i = 0; i < MT; i++)
#pragma unroll
    for (int j = 0; j < NT; j++) { acc[i][j][0] = 0.f; acc[i][j][1] = 0.f; acc[i][j][2] = 0.f; acc[i][j][3] = 0.f; }

  const short* Ah = (const short*)AhS;
  const short* Am = (const short*)AmS;
  const short* Al = (const short*)AlS;
  const short* Bh = (const short*)BhS;
  const short* Bm = (const short*)BmS;
  const short* Bl = (const short*)BlS;

  const float* Xb = X + (size_t)bz * (size_t)K * NP + (size_t)n_idx * 128;
  const size_t abase = (size_t)m_idx * KCH * (size_t)(BM * 32);

  s16x8 rAh[NA], rAm[NA], rAl[NA];
  float rB[2][8];

  {
    const s16x8* awh = (const s16x8*)(wh + abase);
    const s16x8* awm = (const s16x8*)(wmid + abase);
    const s16x8* awl = (const s16x8*)(wl + abase);
#pragma unroll
    for (int t = 0; t < NA; t++) {
      int u = tid + t * 256;
      if (u < BM * 4) { rAh[t] = awh[u]; rAm[t] = awm[u]; rAl[t] = awl[u]; }
    }
#pragma unroll
    for (int t = 0; t < 2; t++) {
      int u = tid + t * 256;
      int qq = u >> 7, n = u & 127;
      const float* fp = Xb + (size_t)(qq * 8) * NP + n;
#pragma unroll
      for (int j = 0; j < 8; j++) {
        float y = fp[(size_t)j * NP];
        if (BNRELU) y = fmaxf(fmaf(y, bnsc[qq * 8 + j], bnsh[qq * 8 + j]), 0.f);
        rB[t][j] = y;
      }
    }
  }

  for (int kc = 0; kc < KCH; kc++) {
#pragma unroll
    for (int t = 0; t < NA; t++) {
      int u = tid + t * 256;
      if (u < BM * 4) { AhS[u] = rAh[t]; AmS[u] = rAm[t]; AlS[u] = rAl[t]; }
    }
#pragma unroll
    for (int t = 0; t < 2; t++) {
      int u = tid + t * 256;
      s16x8 hv, mv, lv;
#pragma unroll
      for (int j = 0; j < 8; j++) {
        short h, mm, ll; split3(rB[t][j], h, mm, ll);
        hv[j] = h; mv[j] = mm; lv[j] = ll;
      }
      BhS[u] = hv; BmS[u] = mv; BlS[u] = lv;
    }
    __syncthreads();

    if (kc + 1 < KCH) {
      size_t ab = abase + (size_t)(kc + 1) * (size_t)(BM * 32);
      const s16x8* awh = (const s16x8*)(wh + ab);
      const s16x8* awm = (const s16x8*)(wmid + ab);
      const s16x8* awl = (const s16x8*)(wl + ab);
#pragma unroll
      for (int t = 0; t < NA; t++) {
        int u = tid + t * 256;
        if (u < BM * 4) { rAh[t] = awh[u]; rAm[t] = awm[u]; rAl[t] = awl[u]; }
      }
      const int kp = (kc + 1) * 32;
#pragma unroll
      for (int t = 0; t < 2; t++) {
        int u = tid + t * 256;
        int qq = u >> 7, n = u & 127;
        const float* fp = Xb + (size_t)(kp + qq * 8) * NP + n;
#pragma unroll
        for (int j = 0; j < 8; j++) {
          float y = fp[(size_t)j * NP];
          if (BNRELU) y = fmaxf(fmaf(y, bnsc[kp + qq * 8 + j], bnsh[kp + qq * 8 + j]), 0.f);
          rB[t][j] = y;
        }
      }
    }

    s16x8 ah[MT], am[MT], al[MT];
#pragma unroll
    for (int i = 0; i < MT; i++) {
      int off = (q * BM + wm * (MT * 16) + i * 16 + col) * 8;
      ah[i] = *(const s16x8*)(Ah + off);
      am[i] = *(const s16x8*)(Am + off);
      al[i] = *(const s16x8*)(Al + off);
    }
    __builtin_amdgcn_s_setprio(1);
#pragma unroll
    for (int j = 0; j < NT; j++) {
      int offb = (q * 128 + wn * (NT * 16) + j * 16 + col) * 8;
      s16x8 bh = *(const s16x8*)(Bh + offb);
      s16x8 bm = *(const s16x8*)(Bm + offb);
      s16x8 bl = *(const s16x8*)(Bl + offb);
#pragma unroll
      for (int i = 0; i < MT; i++) {
        acc[i][j] = __builtin_amdgcn_mfma_f32_16x16x32_bf16(ah[i], bh, acc[i][j], 0, 0, 0);
        acc[i][j] = __builtin_amdgcn_mfma_f32_16x16x32_bf16(ah[i], bm, acc[i][j], 0, 0, 0);
        acc[i][j] = __builtin_amdgcn_mfma_f32_16x16x32_bf16(am[i], bh, acc[i][j], 0, 0, 0);
        acc[i][j] = __builtin_amdgcn_mfma_f32_16x16x32_bf16(ah[i], bl, acc[i][j], 0, 0, 0);
        acc[i][j] = __builtin_amdgcn_mfma_f32_16x16x32_bf16(am[i], bm, acc[i][j], 0, 0, 0);
        acc[i][j] = __builtin_amdgcn_mfma_f32_16x16x32_bf16(al[i], bh, acc[i][j], 0, 0, 0);
      }
    }
    __builtin_amdgcn_s_setprio(0);
    __syncthreads();
  }
#pragma unroll
  for (int i = 0; i < MT; i++) {
#pragma unroll
    for (int r = 0; r < 4; r++) {
      int m = m_idx * BM + wm * (MT * 16) + i * 16 + q * 4 + r;
      float bv = bias[m];
#pragma unroll
      for (int j = 0; j < NT; j++) {
        int n = n_idx * 128 + wn * (NT * 16) + j * 16 + col;
        Y[((size_t)bz * M + m) * 4096 + n] = acc[i][j][r] + bv;
      }
    }
  }
}

// ---------------- BN (training, batch stats over B and N) per channel
__global__ __launch_bounds__(256) void bnstats(
    const float* __restrict__ Y, const float* __restrict__ g, const float* __restrict__ beta,
    float* __restrict__ scale, float* __restrict__ shift, int C, int N) {
  int c = blockIdx.x;
  float s = 0.f, sq = 0.f;
  for (int b = 0; b < BB; b++) {
    const float* p = Y + ((size_t)b * C + c) * N;
    for (int n = threadIdx.x; n < N; n += 256) { float v = p[n]; s += v; sq += v * v; }
  }
  __shared__ float shs[4], shq[4];
  int lane = threadIdx.x & 63, wid = threadIdx.x >> 6;
  s = waveReduceSum(s); sq = waveReduceSum(sq);
  if (lane == 0) { shs[wid] = s; shq[wid] = sq; }
  __syncthreads();
  if (threadIdx.x == 0) {
    float S = shs[0] + shs[1] + shs[2] + shs[3];
    float Q = shq[0] + shq[1] + shq[2] + shq[3];
    float cnt = (float)(BB * N);
    float mean = S / cnt;
    float var = Q / cnt - mean * mean;
    float sc = g[c] / sqrtf(var + BN_EPS);
    scale[c] = sc; shift[c] = beta[c] - mean * sc;
  }
}

// ---------------- softmax over K (axis=1), write score, lse per (b,n), pi partial sums
__global__ __launch_bounds__(256) void softmax_pi(
    const float* __restrict__ LSm, float* __restrict__ score,
    float* __restrict__ lseArr, float* __restrict__ pi_raw) {
  int gidx = blockIdx.x * 256 + threadIdx.x;
  int b = gidx / NP, n = gidx % NP;
  const float* p = LSm + (size_t)b * KC * NP + n;
  float v[KC];
  float m = -1e30f;
#pragma unroll
  for (int k = 0; k < KC; k++) { v[k] = p[(size_t)k * NP]; m = fmaxf(m, v[k]); }
  float s = 0.f;
#pragma unroll
  for (int k = 0; k < KC; k++) { v[k] = expf(v[k] - m); s += v[k]; }
  float inv = 1.f / s;
  float* qq = score + (size_t)b * KC * NP + n;
#pragma unroll
  for (int k = 0; k < KC; k++) { v[k] *= inv; qq[(size_t)k * NP] = v[k]; }
  lseArr[gidx] = m + logf(s);
  __shared__ float ps[KC];
  if (threadIdx.x < KC) ps[threadIdx.x] = 0.f;
  __syncthreads();
  int lane = threadIdx.x & 63;
#pragma unroll
  for (int k = 0; k < KC; k++) {
    float w = waveReduceSum(v[k]);
    if (lane == 0) atomicAdd(&ps[k], w);
  }
  __syncthreads();
  if (threadIdx.x < KC) atomicAdd(&pi_raw[b * KC + threadIdx.x], ps[threadIdx.x]);
}

// ---------------- vlad accumulation (split over n, atomic)
__global__ __launch_bounds__(256) void vlad_accum(
    const float* __restrict__ feat, const float* __restrict__ score, float* __restrict__ vlad) {
  const int SPLIT_LEN = NP / 8;
  int sp = blockIdx.x, dt = blockIdx.y, b = blockIdx.z;
  int d0 = dt * 128;
  int n_start = sp * SPLIT_LEN;
  __shared__ float As[32][132];
  __shared__ float Bs[32][36];
  int tid = threadIdx.x;
  int tx = tid % 16;
  int ty = tid / 16;
  float acc[8][2] = {};
  const float* fb = feat + (size_t)b * DD * NP;
  const float* sb = score + (size_t)b * KC * NP;
  for (int nc = 0; nc < SPLIT_LEN; nc += 32) {
    int n0 = n_start + nc;
    for (int i = tid; i < 128 * 32; i += 256) {
      int r = i >> 5, c = i & 31;
      As[c][r] = fb[(size_t)(d0 + r) * NP + n0 + c];
    }
    for (int i = tid; i < 32 * 32; i += 256) {
      int r = i >> 5, c = i & 31;
      Bs[c][r] = sb[(size_t)r * NP + n0 + c];
    }
    __syncthreads();
#pragma unroll 4
    for (int kk = 0; kk < 32; kk++) {
      float ra[8], rb[2];
#pragma unroll
      for (int i = 0; i < 8; i++) ra[i] = As[kk][ty * 8 + i];
      rb[0] = Bs[kk][tx * 2]; rb[1] = Bs[kk][tx * 2 + 1];
#pragma unroll
      for (int i = 0; i < 8; i++) { acc[i][0] = fmaf(ra[i], rb[0], acc[i][0]); acc[i][1] = fmaf(ra[i], rb[1], acc[i][1]); }
    }
    __syncthreads();
  }
#pragma unroll
  for (int i = 0; i < 8; i++)
#pragma unroll
    for (int j = 0; j < 2; j++)
      atomicAdd(&vlad[((size_t)b * DD + d0 + ty * 8 + i) * KC + tx * 2 + j], acc[i][j]);
}

// ---------------- vlad finalize + gmax + fused ||mu_k||^2 partials
__global__ __launch_bounds__(256) void vlad_fin(
    float* __restrict__ vlad, const float* __restrict__ pi_raw, float* __restrict__ gmax,
    float* __restrict__ nmusq) {
  int idx = blockIdx.x * 256 + threadIdx.x;
  int b = idx / DD;
  float* p = vlad + (size_t)idx * KC;
  const float* pr = pi_raw + b * KC;
  float gm = -1e30f;
  __shared__ float wk[4][KC];
  int lane = threadIdx.x & 63, wid = threadIdx.x >> 6;
#pragma unroll
  for (int k = 0; k < KC; k++) {
    float v = p[k] / fmaxf(pr[k], 1e-4f);
    p[k] = v;
    gm = fmaxf(gm, v);
    float s2 = waveReduceSum(v * v);
    if (lane == 0) wk[wid][k] = s2;
  }
  gmax[idx] = gm;
  __syncthreads();
  if (threadIdx.x < KC) {
    float t = wk[0][threadIdx.x] + wk[1][threadIdx.x] + wk[2][threadIdx.x] + wk[3][threadIdx.x];
    atomicAdd(&nmusq[b * KC + threadIdx.x], t);
  }
}

// ---------------- cost dot accumulation (split over d, atomic) + fused ||f_n||^2
__global__ __launch_bounds__(256) void cost_accum(
    const float* __restrict__ feat, const float* __restrict__ vlad, float* __restrict__ costd,
    float* __restrict__ nfsq) {
  int sp = blockIdx.x, nt = blockIdx.y, b = blockIdx.z;
  int n0 = nt * 128;
  int d_start = sp * (DD / 4);
  __shared__ float As[32][132];
  __shared__ float Bs[32][36];
  __shared__ float nfs[128];
  int tid = threadIdx.x;
  int tx = tid % 16;
  int ty = tid / 16;
  float acc[8][2] = {};
  float sq = 0.f;
  const float* fb = feat + (size_t)b * DD * NP;
  const float* vb = vlad + (size_t)b * DD * KC;
  for (int dc = 0; dc < DD / 4; dc += 32) {
    int dd0 = d_start + dc;
    for (int i = tid; i < 32 * 128; i += 256) {
      int r = i >> 7, c = i & 127;
      float v = fb[(size_t)(dd0 + r) * NP + n0 + c];
      As[r][c] = v;
      sq = fmaf(v, v, sq);
    }
    for (int i = tid; i < 32 * 32; i += 256) {
      int r = i >> 5, c = i & 31;
      Bs[r][c] = vb[(size_t)(dd0 + r) * KC + c];
    }
    __syncthreads();
#pragma unroll 4
    for (int kk = 0; kk < 32; kk++) {
      float ra[8], rb[2];
#pragma unroll
      for (int i = 0; i < 8; i++) ra[i] = As[kk][ty * 8 + i];
      rb[0] = Bs[kk][tx * 2]; rb[1] = Bs[kk][tx * 2 + 1];
#pragma unroll
      for (int i = 0; i < 8; i++) { acc[i][0] = fmaf(ra[i], rb[0], acc[i][0]); acc[i][1] = fmaf(ra[i], rb[1], acc[i][1]); }
    }
    __syncthreads();
  }
#pragma unroll
  for (int i = 0; i < 8; i++)
#pragma unroll
    for (int j = 0; j < 2; j++)
      atomicAdd(&costd[((size_t)b * NP + n0 + ty * 8 + i) * KC + tx * 2 + j], acc[i][j]);
  if (tid < 128) nfs[tid] = 0.f;
  __syncthreads();
  atomicAdd(&nfs[tid & 127], sq);
  __syncthreads();
  if (tid < 128) atomicAdd(&nfsq[(size_t)b * NP + n0 + tid], nfs[tid]);
}

// ---------------- fused sinkhorn: cost_fin + 25 iterations + loss, ONE launch
// 128 blocks (16 per b, 256 rows each). Cross-block G partials move via SCOPED
// ATOMICS (coherence-point I/O, bypassing the 8 non-coherent per-XCD L2s) so
// NO __threadfence (bulk L2 wb/inv) is needed. Barrier = monotonic per-(b,t)
// counter: arrive with relaxed fetch_add, poll < NJB. Store-before-arrive
// ordering comes from __syncthreads' s_waitcnt vmcnt(0) drain.
__global__ __launch_bounds__(256) void sinkhorn_all(
    const float* __restrict__ costd, const float* __restrict__ nfsq,
    const float* __restrict__ nmusq, float* __restrict__ G,
    const float* __restrict__ LSm, const float* __restrict__ lseArr,
    float* __restrict__ out0, unsigned* __restrict__ bar,
    float logp, float logq) {
  const float EPS = 1e-3f, IEPS = 1000.f;
  int b = blockIdx.x / NJB, j = blockIdx.x % NJB;
  int tid = threadIdx.x;
  int n = j * 256 + tid;
  __shared__ float vsh[KC];
  __shared__ float nmS[KC];
  __shared__ float vals[256][33];   // (u - c)/eps staging, +1 pad
  __shared__ float red[KC][9];      // 8 segment partials per k
  __shared__ float bmS[KC];
  __shared__ float redL[4];

  if (tid < KC) nmS[tid] = fmaxf(sqrtf(nmusq[b * KC + tid]), 1e-12f);
  __syncthreads();

  // load + normalize this thread's cost row into registers (cost_fin folded)
  float c[KC];
  {
    const float* dp = costd + ((size_t)b * NP + n) * KC;
    float nf = fmaxf(sqrtf(nfsq[(size_t)b * NP + n]), 1e-12f);
#pragma unroll
    for (int k = 0; k < KC; k++) c[k] = 2.f - 2.f * dp[k] / (nf * nmS[k]);
  }

  const int kk = tid & 31, seg = tid >> 5;   // reduction mapping: 8 segs x 32 rows
  const int r0 = seg * 32;
  float u = 0.f;

  for (int t = 1; t <= 25; t++) {
    if (tid < KC) {
      float v = 0.f;
      if (t > 1) {
        float* Gp = G + (((size_t)(t - 2) * BB + b) * NJB) * KC * 2;
        float gm[NJB], gs[NJB];
#pragma unroll
        for (int jj = 0; jj < NJB; jj++) {
          gm[jj] = __hip_atomic_load(&Gp[(jj * KC + tid) * 2], __ATOMIC_RELAXED, __HIP_MEMORY_SCOPE_AGENT);
          gs[jj] = __hip_atomic_load(&Gp[(jj * KC + tid) * 2 + 1], __ATOMIC_RELAXED, __HIP_MEMORY_SCOPE_AGENT);
        }
        float m = -1e30f;
#pragma unroll
        for (int jj = 0; jj < NJB; jj++) m = fmaxf(m, gm[jj]);
        float s = 0.f;
#pragma unroll
        for (int jj = 0; jj < NJB; jj++) s += gs[jj] * expf(gm[jj] - m);
        v = EPS * logq - EPS * (m + logf(s));
      }
      vsh[tid] = v;
    }
    __syncthreads();
    // u update for this thread's row (all from regs/LDS-broadcast)
    float m = -1e30f;
#pragma unroll
    for (int k = 0; k < KC; k++) m = fmaxf(m, vsh[k] - c[k]);
    float s = 0.f;
#pragma unroll
    for (int k = 0; k < KC; k++) s += expf((vsh[k] - c[k] - m) * IEPS);
    u = EPS * logp - m - EPS * logf(s);
    // stage scaled values for the per-k block reduction
#pragma unroll
    for (int k = 0; k < KC; k++) vals[tid][k] = (u - c[k]) * IEPS;
    __syncthreads();
    // per-k max over this block's 256 rows (8 segments of 32)
    {
      float lm = -1e30f;
      for (int r = 0; r < 32; r++) lm = fmaxf(lm, vals[r0 + r][kk]);
      red[kk][seg] = lm;
    }
    __syncthreads();
    if (tid < KC) {
      float bm = red[tid][0];
      for (int i2 = 1; i2 < 8; i2++) bm = fmaxf(bm, red[tid][i2]);
      bmS[tid] = bm;
    }
    __syncthreads();
    {
      float bm = bmS[kk];
      float ls = 0.f;
      for (int r = 0; r < 32; r++) ls += expf(vals[r0 + r][kk] - bm);
      red[kk][seg] = ls;
    }
    __syncthreads();
    if (tid < KC) {
      float s8 = 0.f;
      for (int i2 = 0; i2 < 8; i2++) s8 += red[tid][i2];
      float* Gp = G + ((((size_t)(t - 1) * BB + b) * NJB + j) * KC + tid) * 2;
      __hip_atomic_store(&Gp[0], bmS[tid], __ATOMIC_RELAXED, __HIP_MEMORY_SCOPE_AGENT);
      __hip_atomic_store(&Gp[1], s8, __ATOMIC_RELAXED, __HIP_MEMORY_SCOPE_AGENT);
    }
    // monotonic per-(b,t) barrier (no reset -> no release-ordering hazard)
    __syncthreads();   // drains each thread's scoped G stores (vmcnt 0) before arrival
    if (tid == 0) {
      unsigned* ct = bar + ((size_t)(t - 1) * BB + b) * 16;   // 64B-spaced counters
      __hip_atomic_fetch_add(ct, 1u, __ATOMIC_RELAXED, __HIP_MEMORY_SCOPE_AGENT);
      while (__hip_atomic_load(ct, __ATOMIC_RELAXED, __HIP_MEMORY_SCOPE_AGENT) < NJB)
        __builtin_amdgcn_s_sleep(2);
    }
    __syncthreads();
  }

  // ---- loss: u currently holds u25 (computed from v24 in iteration 25)
  __shared__ float v25S[KC];
  if (tid < KC) {
    float* Gp = G + (((size_t)24 * BB + b) * NJB) * KC * 2;
    float gm[NJB], gs[NJB];
#pragma unroll
    for (int jj = 0; jj < NJB; jj++) {
      gm[jj] = __hip_atomic_load(&Gp[(jj * KC + tid) * 2], __ATOMIC_RELAXED, __HIP_MEMORY_SCOPE_AGENT);
      gs[jj] = __hip_atomic_load(&Gp[(jj * KC + tid) * 2 + 1], __ATOMIC_RELAXED, __HIP_MEMORY_SCOPE_AGENT);
    }
    float m = -1e30f;
#pragma unroll
    for (int jj = 0; jj < NJB; jj++) m = fmaxf(m, gm[jj]);
    float s = 0.f;
#pragma unroll
    for (int jj = 0; jj < NJB; jj++) s += gs[jj] * expf(gm[jj] - m);
    v25S[tid] = EPS * logq - EPS * (m + logf(s));
  }
  __syncthreads();
  float lsev = lseArr[(size_t)b * NP + n];
  float part = 0.f;
#pragma unroll
  for (int k = 0; k < KC; k++) {
    float gamma = expf((u + v25S[k] - c[k]) * IEPS);
    float logsm = LSm[((size_t)b * KC + k) * NP + n] - lsev;
    part += gamma * logsm;
  }
  part *= (float)NP;
  int lane = tid & 63, wid = tid >> 6;
  part = waveReduceSum(part);
  if (lane == 0) redL[wid] = part;
  __syncthreads();
  if (tid == 0) {
    float tt = redL[0] + redL[1] + redL[2] + redL[3];
    atomicAdd(out0, -tt / (float)(BB * NP));
  }
}

// ---------------- tiled f32 conv1x1 GEMM (projector head, N=32 tiny)
template<int BM, int BN, int BK, int TM, int TN, bool BNRELU>
__global__ __launch_bounds__(256) void gemm_conv(
    const float* __restrict__ W, const float* __restrict__ bias,
    const float* __restrict__ X, float* __restrict__ Y,
    const float* __restrict__ bnscale, const float* __restrict__ bnshift,
    int M, int K, int N) {
  __shared__ float As[BK][BM + 4];
  __shared__ float Xs[BK][BN + 4];
  const int b = blockIdx.z;
  const int m0 = blockIdx.y * BM;
  const int n0 = blockIdx.x * BN;
  const int tid = threadIdx.x;
  const int tx = tid % (BN / TN);
  const int ty = tid / (BN / TN);
  const float* Xb = X + (size_t)b * K * N;
  float acc[TM][TN];
#pragma unroll
  for (int i = 0; i < TM; i++)
#pragma unroll
    for (int j = 0; j < TN; j++) acc[i][j] = 0.f;

  for (int k0 = 0; k0 < K; k0 += BK) {
    for (int i = tid; i < BM * BK; i += 256) {
      int r = i / BK, c = i % BK;
      As[c][r] = W[(size_t)(m0 + r) * K + k0 + c];
    }
    for (int i = tid; i < BK * BN; i += 256) {
      int r = i / BN, c = i % BN;
      float x = Xb[(size_t)(k0 + r) * N + n0 + c];
      if (BNRELU) x = fmaxf(fmaf(x, bnscale[k0 + r], bnshift[k0 + r]), 0.f);
      Xs[r][c] = x;
    }
    __syncthreads();
#pragma unroll 4
    for (int kk = 0; kk < BK; kk++) {
      float ra[TM], rb[TN];
#pragma unroll
      for (int i = 0; i < TM; i++) ra[i] = As[kk][ty * TM + i];
#pragma unroll
      for (int j = 0; j < TN; j++) rb[j] = Xs[kk][tx * TN + j];
#pragma unroll
      for (int i = 0; i < TM; i++)
#pragma unroll
        for (int j = 0; j < TN; j++) acc[i][j] = fmaf(ra[i], rb[j], acc[i][j]);
    }
    __syncthreads();
  }
#pragma unroll
  for (int i = 0; i < TM; i++) {
    float bm = bias[m0 + ty * TM + i];
#pragma unroll
    for (int j = 0; j < TN; j++)
      Y[((size_t)b * M + m0 + ty * TM + i) * N + n0 + tx * TN + j] = acc[i][j] + bm;
  }
}

// ---------------- tiny MLP gemm: one wave per output element
template<bool BNRELU>
__global__ __launch_bounds__(256) void mlp_gemm(
    const float* __restrict__ W, const float* __restrict__ bias,
    const float* __restrict__ in, float* __restrict__ out,
    const float* __restrict__ sc, const float* __restrict__ sh, int M, int K) {
  int gw = (blockIdx.x * 256 + threadIdx.x) >> 6;   // global wave id = output idx
  int lane = threadIdx.x & 63;
  int s = gw / M, jj = gw % M;
  const float4* ip = (const float4*)(in + (size_t)s * K);
  const float4* wp = (const float4*)(W + (size_t)jj * K);
  float acc = 0.f;
  for (int c4 = lane; c4 < (K >> 2); c4 += 64) {
    float4 x = ip[c4];
    float4 w = wp[c4];
    if (BNRELU) {
      int cb = c4 * 4;
      x.x = fmaxf(fmaf(x.x, sc[cb + 0], sh[cb + 0]), 0.f);
      x.y = fmaxf(fmaf(x.y, sc[cb + 1], sh[cb + 1]), 0.f);
      x.z = fmaxf(fmaf(x.z, sc[cb + 2], sh[cb + 2]), 0.f);
      x.w = fmaxf(fmaf(x.w, sc[cb + 3], sh[cb + 3]), 0.f);
    }
    acc += x.x * w.x + x.y * w.y + x.z * w.z + x.w * w.w;
  }
  acc = waveReduceSum(acc);
  if (lane == 0) out[gw] = acc + bias[jj];
}

__global__ __launch_bounds__(256) void mlp_bnstats(
    const float* __restrict__ mat, const float* __restrict__ g, const float* __restrict__ beta,
    float* __restrict__ scale, float* __restrict__ shift, int M) {
  int j = blockIdx.x * 256 + threadIdx.x;
  if (j >= M) return;
  float s = 0.f, sq = 0.f;
  for (int si = 0; si < BB; si++) { float v = mat[si * M + j]; s += v; sq += v * v; }
  float mean = s / (float)BB;
  float var = sq / (float)BB - mean * mean;
  float sc = g[j] / sqrtf(var + BN_EPS);
  scale[j] = sc; shift[j] = beta[j] - mean * sc;
}

// ---------------- launch ----------------
extern "C" void kernel_launch(void* const* d_in, const int* in_sizes, int n_in,
                              void* d_out, int out_size, void* d_ws, size_t ws_size,
                              hipStream_t stream) {
  const float* feat = (const float*)d_in[0];
  const float* cw1 = (const float*)d_in[1];  const float* cb1 = (const float*)d_in[2];
  const float* cg1 = (const float*)d_in[3];  const float* ct1 = (const float*)d_in[4];
  const float* cw2 = (const float*)d_in[5];  const float* cb2 = (const float*)d_in[6];
  const float* cg2 = (const float*)d_in[7];  const float* ct2 = (const float*)d_in[8];
  const float* cw3 = (const float*)d_in[9];  const float* cb3 = (const float*)d_in[10];
  const float* pw1 = (const float*)d_in[11]; const float* pb1 = (const float*)d_in[12];
  const float* pg1 = (const float*)d_in[13]; const float* pt1 = (const float*)d_in[14];
  const float* pw2 = (const float*)d_in[15]; const float* pb2 = (const float*)d_in[16];
  const float* pg2 = (const float*)d_in[17]; const float* pt2 = (const float*)d_in[18];
  const float* pw3 = (const float*)d_in[19]; const float* pb3 = (const float*)d_in[20];
  const float* mw1 = (const float*)d_in[21]; const float* mb1 = (const float*)d_in[22];
  const float* mg1 = (const float*)d_in[23]; const float* mt1 = (const float*)d_in[24];
  const float* mw2 = (const float*)d_in[25]; const float* mb2 = (const float*)d_in[26];
  const float* mg2 = (const float*)d_in[27]; const float* mt2 = (const float*)d_in[28];
  const float* mw3 = (const float*)d_in[29]; const float* mb3 = (const float*)d_in[30];
  float* out = (float*)d_out;

  // ---- workspace layout: post-GEMM2 buffers alias Y1 ----
  char* p = (char*)d_ws;
  size_t off = 0;
  auto alloc = [&](size_t bytes) { char* r = p + off; off = (off + bytes + 255) & ~(size_t)255; return r; };
  float* Y1 = (float*)alloc(67108864);   // [8][512][4096] f32
  float* Y2 = (float*)alloc(67108864);
  u16* W1H = (u16*)alloc(1048576); u16* W1M = (u16*)alloc(1048576); u16* W1L = (u16*)alloc(1048576);
  u16* W2H = (u16*)alloc(524288);  u16* W2M = (u16*)alloc(524288);  u16* W2L = (u16*)alloc(524288);
  u16* W3H = (u16*)alloc(32768);   u16* W3M = (u16*)alloc(32768);   u16* W3L = (u16*)alloc(32768);
  float* SC1  = (float*)alloc(2048); float* SH1 = (float*)alloc(2048);
  float* SC2  = (float*)alloc(2048); float* SH2 = (float*)alloc(2048);
  float* PSC1 = (float*)alloc(2048); float* PSH1 = (float*)alloc(2048);
  float* PSC2 = (float*)alloc(2048); float* PSH2 = (float*)alloc(2048);
  float* MSC1 = (float*)alloc(2048); float* MSH1 = (float*)alloc(2048);
  float* MSC2 = (float*)alloc(2048); float* MSH2 = (float*)alloc(2048);
  // ---- sub-arena inside Y1's region: first written AFTER GEMM2 completes ----
  char* q = (char*)Y1;
  size_t qoff = 0;
  auto qalloc = [&](size_t bytes) { char* r = q + qoff; qoff = (qoff + bytes + 255) & ~(size_t)255; return r; };
  float* LSC  = (float*)qalloc(4194304);  // [8][32][4096], written by GEMM3
  float* SCRB = (float*)qalloc(4194304);  // score
  float* LSE  = (float*)qalloc(131072);
  float* GBUF = (float*)qalloc(819200);   // 25*8*16*32*2 floats
  float* GMAX = (float*)qalloc(32768);
  float* MH1  = (float*)qalloc(16384);
  float* MH2  = (float*)qalloc(16384);
  float* T1   = (float*)qalloc(524288);
  float* T2   = (float*)qalloc(524288);
  // contiguous memset region: PIRAW | VLAD | COSTD | NFSQ | NMUSQ | BAR(16KB)
  const size_t MS_BYTES = 1024 + 1048576 + 4194304 + 131072 + 1024 + 16384;
  char* MS = qalloc(MS_BYTES);
  float* PIRAW = (float*)MS;
  float* VLAD  = (float*)(MS + 1024);
  float* COSTD = (float*)(MS + 1024 + 1048576);
  float* NFSQ  = (float*)(MS + 1024 + 1048576 + 4194304);
  float* NMUSQ = (float*)(MS + 1024 + 1048576 + 4194304 + 131072);
  unsigned* BAR = (unsigned*)(MS + 1024 + 1048576 + 4194304 + 131072 + 1024);

  hipMemsetAsync(d_out, 0, sizeof(float), stream);

  float logp = logf(1.0f / NP + 1e-8f);
  float logq = logf(1.0f / KC + 1e-8f);
  dim3 blk(256);

  // weight permute + 3-split (all three sets, one launch)
  convW3_all<<<dim3(4, 32, 3), blk, 0, stream>>>(
      cw1, W1H, W1M, W1L, cw2, W2H, W2M, W2L, cw3, W3H, W3M, W3L);

  // score head: bf16x3 MFMA (f32-equivalent), reg-prefetch pipelined
  gemm_mfma3<128, 4, 4, 4, 2, false><<<dim3(128, 1, 8), blk, 0, stream>>>(
      W1H, W1M, W1L, cb1, feat, nullptr, nullptr, Y1, 1024, 512);
  bnstats<<<dim3(512), blk, 0, stream>>>(Y1, cg1, ct1, SC1, SH1, 512, NP);
  gemm_mfma3<128, 4, 4, 4, 2, true><<<dim3(128, 1, 8), blk, 0, stream>>>(
      W2H, W2M, W2L, cb2, Y1, SC1, SH1, Y2, 512, 512);
  bnstats<<<dim3(512), blk, 0, stream>>>(Y2, cg2, ct2, SC2, SH2, 512, NP);
  // Y1 is now dead -> zero the aliased accumulation buffers inside it
  hipMemsetAsync(MS, 0, MS_BYTES, stream);
  gemm_mfma3<32, 1, 2, 2, 1, true><<<dim3(32, 1, 8), blk, 0, stream>>>(
      W3H, W3M, W3L, cb3, Y2, SC2, SH2, LSC, 512, 32);

  // softmax + pi + lse
  softmax_pi<<<dim3(BB * NP / 256), blk, 0, stream>>>(LSC, SCRB, LSE, PIRAW);

  // vlad (+ fused ||mu||^2)
  vlad_accum<<<dim3(8, DD / 128, BB), blk, 0, stream>>>(feat, SCRB, VLAD);
  vlad_fin<<<dim3(BB * DD / 256), blk, 0, stream>>>(VLAD, PIRAW, GMAX, NMUSQ);

  // cost dots (+ fused ||f||^2)
  cost_accum<<<dim3(4, NP / 128, BB), blk, 0, stream>>>(feat, VLAD, COSTD, NFSQ);

  // fused sinkhorn: normalize + 25 iterations + loss in ONE launch
  // (scoped-atomic G exchange + monotonic counters; no __threadfence)
  sinkhorn_all<<<dim3(BB * NJB), blk, 0, stream>>>(
      COSTD, NFSQ, NMUSQ, GBUF, LSC, LSE, out, BAR, logp, logq);

  // predictor MLP on max-pooled vlad (wave-per-output, multi-block)
  mlp_gemm<false><<<dim3(BB * HH / 4), blk, 0, stream>>>(mw1, mb1, GMAX, MH1, nullptr, nullptr, HH, DD);
  mlp_bnstats<<<dim3(2), blk, 0, stream>>>(MH1, mg1, mt1, MSC1, MSH1, HH);
  mlp_gemm<true><<<dim3(BB * HH / 4), blk, 0, stream>>>(mw2, mb2, MH1, MH2, MSC1, MSH1, HH, HH);
  mlp_bnstats<<<dim3(2), blk, 0, stream>>>(MH2, mg2, mt2, MSC2, MSH2, HH);
  mlp_gemm<true><<<dim3(BB * PP / 4), blk, 0, stream>>>(mw3, mb3, MH2, out + 1 + BB * PP * KC, MSC2, MSH2, PP, HH);

  // projector conv head on vlad (N=32, f32)
  gemm_conv<64, 32, 16, 4, 2, false><<<dim3(1, HH / 64, BB), blk, 0, stream>>>(pw1, pb1, VLAD, T1, nullptr, nullptr, HH, DD, KC);
  bnstats<<<dim3(512), blk, 0, stream>>>(T1, pg1, pt1, PSC1, PSH1, HH, KC);
  gemm_conv<64, 32, 16, 4, 2, true><<<dim3(1, HH / 64, BB), blk, 0, stream>>>(pw2, pb2, T1, T2, PSC1, PSH1, HH, HH, KC);
  bnstats<<<dim3(512), blk, 0, stream>>>(T2, pg2, pt2, PSC2, PSH2, HH, KC);
  gemm_conv<64, 32, 16, 4, 2, true><<<dim3(1, PP / 64, BB), blk, 0, stream>>>(pw3, pb3, T2, out + 1, PSC2, PSH2, PP, HH, KC);
}

// Round 7
// 1221.704 us; speedup vs baseline: 2.0624x; 1.0040x over previous
//
#include <hip/hip_runtime.h>
#include <cmath>

#define BB 8
#define DD 1024
#define NP 4096
#define KC 32
#define HH 512
#define PP 128
#define NJB 16          // sinkhorn blocks per batch
#define BN_EPS 1e-5f

typedef unsigned short u16;
typedef unsigned long long u64;
typedef short s16x8 __attribute__((ext_vector_type(8)));
typedef float f32x4 __attribute__((ext_vector_type(4)));

// ---------------- wave helpers ----------------
__device__ __forceinline__ float waveReduceSum(float v) {
#pragma unroll
  for (int o = 32; o > 0; o >>= 1) v += __shfl_down(v, o, 64);
  return v;
}

// ---------------- bf16 3-way split: y = h + m + l + O(2^-24 |y|) ----------
__device__ __forceinline__ void split3(float y, short& h, short& m, short& l) {
  unsigned uy = __float_as_uint(y);
  h = (short)(uy >> 16);
  float r1 = y - __uint_as_float(uy & 0xFFFF0000u);
  unsigned um = __float_as_uint(r1);
  m = (short)(um >> 16);
  float r2 = r1 - __uint_as_float(um & 0xFFFF0000u);
  l = (short)(__float_as_uint(r2) >> 16);
}

// ---------------- W pre-permute + 3-split, all three weight sets in one launch
__global__ __launch_bounds__(256) void convW3_all(
    const float* __restrict__ W1, u16* __restrict__ h1, u16* __restrict__ m1, u16* __restrict__ l1,
    const float* __restrict__ W2, u16* __restrict__ h2, u16* __restrict__ m2, u16* __restrict__ l2,
    const float* __restrict__ W3, u16* __restrict__ h3, u16* __restrict__ m3, u16* __restrict__ l3) {
  int z = blockIdx.z;
  const float* W; u16 *hb, *mb, *lb; int K, BM, MTt, KCH;
  if (z == 0)      { W = W1; hb = h1; mb = m1; lb = l1; K = 1024; BM = 128; MTt = 4; KCH = 32; }
  else if (z == 1) { W = W2; hb = h2; mb = m2; lb = l2; K = 512;  BM = 128; MTt = 4; KCH = 16; }
  else             { W = W3; hb = h3; mb = m3; lb = l3; K = 512;  BM = 32;  MTt = 1; KCH = 16; }
  int mt = blockIdx.x, kc = blockIdx.y;
  if (mt >= MTt || kc >= KCH) return;
  const int AU = BM * 4;
  for (int u = threadIdx.x; u < AU; u += 256) {
    int q = u / BM, m = u % BM;
    const float* wp = W + (size_t)(mt * BM + m) * K + kc * 32 + q * 8;
    s16x8 hv, mv, lv;
#pragma unroll
    for (int j = 0; j < 8; j++) {
      short h, mm, l; split3(wp[j], h, mm, l);
      hv[j] = h; mv[j] = mm; lv[j] = l;
    }
    size_t ob = ((size_t)(mt * KCH + kc)) * (size_t)(BM * 32) + (size_t)u * 8;
    *(s16x8*)(hb + ob) = hv;
    *(s16x8*)(mb + ob) = mv;
    *(s16x8*)(lb + ob) = lv;
  }
}

// ---------------- bf16x3 MFMA GEMM (f32-equivalent), reg-prefetch pipelined
template<int BM, int MBLK, int MT, int NT, int WM, bool BNRELU>
__global__ __launch_bounds__(256) void gemm_mfma3(
    const u16* __restrict__ wh, const u16* __restrict__ wmid, const u16* __restrict__ wl,
    const float* __restrict__ bias, const float* __restrict__ X,
    const float* __restrict__ bnsc, const float* __restrict__ bnsh,
    float* __restrict__ Y, int K, int M) {
  __shared__ s16x8 AhS[BM * 4], AmS[BM * 4], AlS[BM * 4];
  __shared__ s16x8 BhS[512], BmS[512], BlS[512];
  const int KCH = K / 32;
  const int tid = threadIdx.x;
  const int bz = blockIdx.z;
  int bid = blockIdx.x;
  int xs = bid & 7, rr = bid >> 3;
  int m_idx = rr % MBLK;
  int n_idx = xs + 8 * (rr / MBLK);

  const int w = tid >> 6, l = tid & 63, q = l >> 4, col = l & 15;
  const int wm = (WM == 1) ? 0 : (w >> 1);
  const int wn = (WM == 1) ? w : (w & 1);
  constexpr int NA = (BM * 4 + 255) / 256;

  f32x4 acc[MT][NT];
#pragma unroll
  for (int i = 0; i < MT; i++)
#pragma unroll
    for (int j = 0; j < NT; j++) { acc[i][j][0] = 0.f; acc[i][j][1] = 0.f; acc[i][j][2] = 0.f; acc[i][j][3] = 0.f; }

  const short* Ah = (const short*)AhS;
  const short* Am = (const short*)AmS;
  const short* Al = (const short*)AlS;
  const short* Bh = (const short*)BhS;
  const short* Bm = (const short*)BmS;
  const short* Bl = (const short*)BlS;

  const float* Xb = X + (size_t)bz * (size_t)K * NP + (size_t)n_idx * 128;
  const size_t abase = (size_t)m_idx * KCH * (size_t)(BM * 32);

  s16x8 rAh[NA], rAm[NA], rAl[NA];
  float rB[2][8];

  {
    const s16x8* awh = (const s16x8*)(wh + abase);
    const s16x8* awm = (const s16x8*)(wmid + abase);
    const s16x8* awl = (const s16x8*)(wl + abase);
#pragma unroll
    for (int t = 0; t < NA; t++) {
      int u = tid + t * 256;
      if (u < BM * 4) { rAh[t] = awh[u]; rAm[t] = awm[u]; rAl[t] = awl[u]; }
    }
#pragma unroll
    for (int t = 0; t < 2; t++) {
      int u = tid + t * 256;
      int qq = u >> 7, n = u & 127;
      const float* fp = Xb + (size_t)(qq * 8) * NP + n;
#pragma unroll
      for (int j = 0; j < 8; j++) {
        float y = fp[(size_t)j * NP];
        if (BNRELU) y = fmaxf(fmaf(y, bnsc[qq * 8 + j], bnsh[qq * 8 + j]), 0.f);
        rB[t][j] = y;
      }
    }
  }

  for (int kc = 0; kc < KCH; kc++) {
#pragma unroll
    for (int t = 0; t < NA; t++) {
      int u = tid + t * 256;
      if (u < BM * 4) { AhS[u] = rAh[t]; AmS[u] = rAm[t]; AlS[u] = rAl[t]; }
    }
#pragma unroll
    for (int t = 0; t < 2; t++) {
      int u = tid + t * 256;
      s16x8 hv, mv, lv;
#pragma unroll
      for (int j = 0; j < 8; j++) {
        short h, mm, ll; split3(rB[t][j], h, mm, ll);
        hv[j] = h; mv[j] = mm; lv[j] = ll;
      }
      BhS[u] = hv; BmS[u] = mv; BlS[u] = lv;
    }
    __syncthreads();

    if (kc + 1 < KCH) {
      size_t ab = abase + (size_t)(kc + 1) * (size_t)(BM * 32);
      const s16x8* awh = (const s16x8*)(wh + ab);
      const s16x8* awm = (const s16x8*)(wmid + ab);
      const s16x8* awl = (const s16x8*)(wl + ab);
#pragma unroll
      for (int t = 0; t < NA; t++) {
        int u = tid + t * 256;
        if (u < BM * 4) { rAh[t] = awh[u]; rAm[t] = awm[u]; rAl[t] = awl[u]; }
      }
      const int kp = (kc + 1) * 32;
#pragma unroll
      for (int t = 0; t < 2; t++) {
        int u = tid + t * 256;
        int qq = u >> 7, n = u & 127;
        const float* fp = Xb + (size_t)(kp + qq * 8) * NP + n;
#pragma unroll
        for (int j = 0; j < 8; j++) {
          float y = fp[(size_t)j * NP];
          if (BNRELU) y = fmaxf(fmaf(y, bnsc[kp + qq * 8 + j], bnsh[kp + qq * 8 + j]), 0.f);
          rB[t][j] = y;
        }
      }
    }

    s16x8 ah[MT], am[MT], al[MT];
#pragma unroll
    for (int i = 0; i < MT; i++) {
      int off = (q * BM + wm * (MT * 16) + i * 16 + col) * 8;
      ah[i] = *(const s16x8*)(Ah + off);
      am[i] = *(const s16x8*)(Am + off);
      al[i] = *(const s16x8*)(Al + off);
    }
    __builtin_amdgcn_s_setprio(1);
#pragma unroll
    for (int j = 0; j < NT; j++) {
      int offb = (q * 128 + wn * (NT * 16) + j * 16 + col) * 8;
      s16x8 bh = *(const s16x8*)(Bh + offb);
      s16x8 bm = *(const s16x8*)(Bm + offb);
      s16x8 bl = *(const s16x8*)(Bl + offb);
#pragma unroll
      for (int i = 0; i < MT; i++) {
        acc[i][j] = __builtin_amdgcn_mfma_f32_16x16x32_bf16(ah[i], bh, acc[i][j], 0, 0, 0);
        acc[i][j] = __builtin_amdgcn_mfma_f32_16x16x32_bf16(ah[i], bm, acc[i][j], 0, 0, 0);
        acc[i][j] = __builtin_amdgcn_mfma_f32_16x16x32_bf16(am[i], bh, acc[i][j], 0, 0, 0);
        acc[i][j] = __builtin_amdgcn_mfma_f32_16x16x32_bf16(ah[i], bl, acc[i][j], 0, 0, 0);
        acc[i][j] = __builtin_amdgcn_mfma_f32_16x16x32_bf16(am[i], bm, acc[i][j], 0, 0, 0);
        acc[i][j] = __builtin_amdgcn_mfma_f32_16x16x32_bf16(al[i], bh, acc[i][j], 0, 0, 0);
      }
    }
    __builtin_amdgcn_s_setprio(0);
    __syncthreads();
  }
#pragma unroll
  for (int i = 0; i < MT; i++) {
#pragma unroll
    for (int r = 0; r < 4; r++) {
      int m = m_idx * BM + wm * (MT * 16) + i * 16 + q * 4 + r;
      float bv = bias[m];
#pragma unroll
      for (int j = 0; j < NT; j++) {
        int n = n_idx * 128 + wn * (NT * 16) + j * 16 + col;
        Y[((size_t)bz * M + m) * 4096 + n] = acc[i][j][r] + bv;
      }
    }
  }
}

// ---------------- BN (training, batch stats over B and N) per channel
__global__ __launch_bounds__(256) void bnstats(
    const float* __restrict__ Y, const float* __restrict__ g, const float* __restrict__ beta,
    float* __restrict__ scale, float* __restrict__ shift, int C, int N) {
  int c = blockIdx.x;
  float s = 0.f, sq = 0.f;
  for (int b = 0; b < BB; b++) {
    const float* p = Y + ((size_t)b * C + c) * N;
    for (int n = threadIdx.x; n < N; n += 256) { float v = p[n]; s += v; sq += v * v; }
  }
  __shared__ float shs[4], shq[4];
  int lane = threadIdx.x & 63, wid = threadIdx.x >> 6;
  s = waveReduceSum(s); sq = waveReduceSum(sq);
  if (lane == 0) { shs[wid] = s; shq[wid] = sq; }
  __syncthreads();
  if (threadIdx.x == 0) {
    float S = shs[0] + shs[1] + shs[2] + shs[3];
    float Q = shq[0] + shq[1] + shq[2] + shq[3];
    float cnt = (float)(BB * N);
    float mean = S / cnt;
    float var = Q / cnt - mean * mean;
    float sc = g[c] / sqrtf(var + BN_EPS);
    scale[c] = sc; shift[c] = beta[c] - mean * sc;
  }
}

// ---------------- softmax over K (axis=1), write score, lse per (b,n), pi partial sums
__global__ __launch_bounds__(256) void softmax_pi(
    const float* __restrict__ LSm, float* __restrict__ score,
    float* __restrict__ lseArr, float* __restrict__ pi_raw) {
  int gidx = blockIdx.x * 256 + threadIdx.x;
  int b = gidx / NP, n = gidx % NP;
  const float* p = LSm + (size_t)b * KC * NP + n;
  float v[KC];
  float m = -1e30f;
#pragma unroll
  for (int k = 0; k < KC; k++) { v[k] = p[(size_t)k * NP]; m = fmaxf(m, v[k]); }
  float s = 0.f;
#pragma unroll
  for (int k = 0; k < KC; k++) { v[k] = expf(v[k] - m); s += v[k]; }
  float inv = 1.f / s;
  float* qq = score + (size_t)b * KC * NP + n;
#pragma unroll
  for (int k = 0; k < KC; k++) { v[k] *= inv; qq[(size_t)k * NP] = v[k]; }
  lseArr[gidx] = m + logf(s);
  __shared__ float ps[KC];
  if (threadIdx.x < KC) ps[threadIdx.x] = 0.f;
  __syncthreads();
  int lane = threadIdx.x & 63;
#pragma unroll
  for (int k = 0; k < KC; k++) {
    float w = waveReduceSum(v[k]);
    if (lane == 0) atomicAdd(&ps[k], w);
  }
  __syncthreads();
  if (threadIdx.x < KC) atomicAdd(&pi_raw[b * KC + threadIdx.x], ps[threadIdx.x]);
}

// ---------------- vlad accumulation (split over n, atomic)
__global__ __launch_bounds__(256) void vlad_accum(
    const float* __restrict__ feat, const float* __restrict__ score, float* __restrict__ vlad) {
  const int SPLIT_LEN = NP / 8;
  int sp = blockIdx.x, dt = blockIdx.y, b = blockIdx.z;
  int d0 = dt * 128;
  int n_start = sp * SPLIT_LEN;
  __shared__ float As[32][132];
  __shared__ float Bs[32][36];
  int tid = threadIdx.x;
  int tx = tid % 16;
  int ty = tid / 16;
  float acc[8][2] = {};
  const float* fb = feat + (size_t)b * DD * NP;
  const float* sb = score + (size_t)b * KC * NP;
  for (int nc = 0; nc < SPLIT_LEN; nc += 32) {
    int n0 = n_start + nc;
    for (int i = tid; i < 128 * 32; i += 256) {
      int r = i >> 5, c = i & 31;
      As[c][r] = fb[(size_t)(d0 + r) * NP + n0 + c];
    }
    for (int i = tid; i < 32 * 32; i += 256) {
      int r = i >> 5, c = i & 31;
      Bs[c][r] = sb[(size_t)r * NP + n0 + c];
    }
    __syncthreads();
#pragma unroll 4
    for (int kk = 0; kk < 32; kk++) {
      float ra[8], rb[2];
#pragma unroll
      for (int i = 0; i < 8; i++) ra[i] = As[kk][ty * 8 + i];
      rb[0] = Bs[kk][tx * 2]; rb[1] = Bs[kk][tx * 2 + 1];
#pragma unroll
      for (int i = 0; i < 8; i++) { acc[i][0] = fmaf(ra[i], rb[0], acc[i][0]); acc[i][1] = fmaf(ra[i], rb[1], acc[i][1]); }
    }
    __syncthreads();
  }
#pragma unroll
  for (int i = 0; i < 8; i++)
#pragma unroll
    for (int j = 0; j < 2; j++)
      atomicAdd(&vlad[((size_t)b * DD + d0 + ty * 8 + i) * KC + tx * 2 + j], acc[i][j]);
}

// ---------------- vlad finalize + gmax + fused ||mu_k||^2 partials
__global__ __launch_bounds__(256) void vlad_fin(
    float* __restrict__ vlad, const float* __restrict__ pi_raw, float* __restrict__ gmax,
    float* __restrict__ nmusq) {
  int idx = blockIdx.x * 256 + threadIdx.x;
  int b = idx / DD;
  float* p = vlad + (size_t)idx * KC;
  const float* pr = pi_raw + b * KC;
  float gm = -1e30f;
  __shared__ float wk[4][KC];
  int lane = threadIdx.x & 63, wid = threadIdx.x >> 6;
#pragma unroll
  for (int k = 0; k < KC; k++) {
    float v = p[k] / fmaxf(pr[k], 1e-4f);
    p[k] = v;
    gm = fmaxf(gm, v);
    float s2 = waveReduceSum(v * v);
    if (lane == 0) wk[wid][k] = s2;
  }
  gmax[idx] = gm;
  __syncthreads();
  if (threadIdx.x < KC) {
    float t = wk[0][threadIdx.x] + wk[1][threadIdx.x] + wk[2][threadIdx.x] + wk[3][threadIdx.x];
    atomicAdd(&nmusq[b * KC + threadIdx.x], t);
  }
}

// ---------------- cost dot accumulation (split over d, atomic) + fused ||f_n||^2
__global__ __launch_bounds__(256) void cost_accum(
    const float* __restrict__ feat, const float* __restrict__ vlad, float* __restrict__ costd,
    float* __restrict__ nfsq) {
  int sp = blockIdx.x, nt = blockIdx.y, b = blockIdx.z;
  int n0 = nt * 128;
  int d_start = sp * (DD / 4);
  __shared__ float As[32][132];
  __shared__ float Bs[32][36];
  __shared__ float nfs[128];
  int tid = threadIdx.x;
  int tx = tid % 16;
  int ty = tid / 16;
  float acc[8][2] = {};
  float sq = 0.f;
  const float* fb = feat + (size_t)b * DD * NP;
  const float* vb = vlad + (size_t)b * DD * KC;
  for (int dc = 0; dc < DD / 4; dc += 32) {
    int dd0 = d_start + dc;
    for (int i = tid; i < 32 * 128; i += 256) {
      int r = i >> 7, c = i & 127;
      float v = fb[(size_t)(dd0 + r) * NP + n0 + c];
      As[r][c] = v;
      sq = fmaf(v, v, sq);
    }
    for (int i = tid; i < 32 * 32; i += 256) {
      int r = i >> 5, c = i & 31;
      Bs[r][c] = vb[(size_t)(dd0 + r) * KC + c];
    }
    __syncthreads();
#pragma unroll 4
    for (int kk = 0; kk < 32; kk++) {
      float ra[8], rb[2];
#pragma unroll
      for (int i = 0; i < 8; i++) ra[i] = As[kk][ty * 8 + i];
      rb[0] = Bs[kk][tx * 2]; rb[1] = Bs[kk][tx * 2 + 1];
#pragma unroll
      for (int i = 0; i < 8; i++) { acc[i][0] = fmaf(ra[i], rb[0], acc[i][0]); acc[i][1] = fmaf(ra[i], rb[1], acc[i][1]); }
    }
    __syncthreads();
  }
#pragma unroll
  for (int i = 0; i < 8; i++)
#pragma unroll
    for (int j = 0; j < 2; j++)
      atomicAdd(&costd[((size_t)b * NP + n0 + ty * 8 + i) * KC + tx * 2 + j], acc[i][j]);
  if (tid < 128) nfs[tid] = 0.f;
  __syncthreads();
  atomicAdd(&nfs[tid & 127], sq);
  __syncthreads();
  if (tid < 128) atomicAdd(&nfsq[(size_t)b * NP + n0 + tid], nfs[tid]);
}

// ---------------- fused sinkhorn: cost_fin + 25 iterations + loss, ONE launch
// 128 blocks (16 per b, 256 rows each). Cross-block G partials move via scoped
// 8-byte atomics (coherence-point I/O; the (max,sum) pair is one u64). Sync is
// DATA-DRIVEN: per-(t,b,j) ready-flags replace the counter barrier — after
// __syncthreads drains a block's G stores (scoped stores count in vmcnt, so
// drain = completion at the coherence point), tid0 sets its flag; the next
// iteration polls the 16 flags then loads G. Removes the fetch_add round trip
// and the convoy effect of a counter barrier. Flags are monotonic (memset 0).
__global__ __launch_bounds__(256) void sinkhorn_all(
    const float* __restrict__ costd, const float* __restrict__ nfsq,
    const float* __restrict__ nmusq, u64* __restrict__ G,
    const float* __restrict__ LSm, const float* __restrict__ lseArr,
    float* __restrict__ out0, unsigned* __restrict__ flags,
    float logp, float logq) {
  const float EPS = 1e-3f, IEPS = 1000.f;
  int b = blockIdx.x / NJB, j = blockIdx.x % NJB;
  int tid = threadIdx.x;
  int n = j * 256 + tid;
  __shared__ float vsh[KC];
  __shared__ float nmS[KC];
  __shared__ float vals[256][33];   // (u - c)/eps staging, +1 pad
  __shared__ float red[KC][9];      // 8 segment partials per k
  __shared__ float bmS[KC];
  __shared__ float redL[4];

  if (tid < KC) nmS[tid] = fmaxf(sqrtf(nmusq[b * KC + tid]), 1e-12f);
  __syncthreads();

  // load + normalize this thread's cost row into registers (cost_fin folded)
  float c[KC];
  {
    const float* dp = costd + ((size_t)b * NP + n) * KC;
    float nf = fmaxf(sqrtf(nfsq[(size_t)b * NP + n]), 1e-12f);
#pragma unroll
    for (int k = 0; k < KC; k++) c[k] = 2.f - 2.f * dp[k] / (nf * nmS[k]);
  }

  const int kk = tid & 31, seg = tid >> 5;   // reduction mapping: 8 segs x 32 rows
  const int r0 = seg * 32;
  float u = 0.f;

  for (int t = 1; t <= 25; t++) {
    if (t > 1) {
      // data-driven wait: all 16 j-partials of iteration t-1 published?
      if (tid < NJB) {
        const unsigned* fp = flags + ((size_t)(t - 2) * BB + b) * NJB;
        while (__hip_atomic_load(&fp[tid], __ATOMIC_RELAXED, __HIP_MEMORY_SCOPE_AGENT) == 0u)
          __builtin_amdgcn_s_sleep(1);
      }
      __syncthreads();
    }
    if (tid < KC) {
      float v = 0.f;
      if (t > 1) {
        const u64* Gp = G + (((size_t)(t - 2) * BB + b) * NJB) * KC;
        float gm[NJB], gs[NJB];
#pragma unroll
        for (int jj = 0; jj < NJB; jj++) {
          u64 raw = __hip_atomic_load(&Gp[jj * KC + tid], __ATOMIC_RELAXED, __HIP_MEMORY_SCOPE_AGENT);
          gm[jj] = __uint_as_float((unsigned)raw);
          gs[jj] = __uint_as_float((unsigned)(raw >> 32));
        }
        float m = -1e30f;
#pragma unroll
        for (int jj = 0; jj < NJB; jj++) m = fmaxf(m, gm[jj]);
        float s = 0.f;
#pragma unroll
        for (int jj = 0; jj < NJB; jj++) s += gs[jj] * expf(gm[jj] - m);
        v = EPS * logq - EPS * (m + logf(s));
      }
      vsh[tid] = v;
    }
    __syncthreads();
    // u update for this thread's row (all from regs/LDS-broadcast)
    float m = -1e30f;
#pragma unroll
    for (int k = 0; k < KC; k++) m = fmaxf(m, vsh[k] - c[k]);
    float s = 0.f;
#pragma unroll
    for (int k = 0; k < KC; k++) s += expf((vsh[k] - c[k] - m) * IEPS);
    u = EPS * logp - m - EPS * logf(s);
    // stage scaled values for the per-k block reduction
#pragma unroll
    for (int k = 0; k < KC; k++) vals[tid][k] = (u - c[k]) * IEPS;
    __syncthreads();
    // per-k max over this block's 256 rows (8 segments of 32)
    {
      float lm = -1e30f;
      for (int r = 0; r < 32; r++) lm = fmaxf(lm, vals[r0 + r][kk]);
      red[kk][seg] = lm;
    }
    __syncthreads();
    if (tid < KC) {
      float bm = red[tid][0];
      for (int i2 = 1; i2 < 8; i2++) bm = fmaxf(bm, red[tid][i2]);
      bmS[tid] = bm;
    }
    __syncthreads();
    {
      float bm = bmS[kk];
      float ls = 0.f;
      for (int r = 0; r < 32; r++) ls += expf(vals[r0 + r][kk] - bm);
      red[kk][seg] = ls;
    }
    __syncthreads();
    if (tid < KC) {
      float s8 = 0.f;
      for (int i2 = 0; i2 < 8; i2++) s8 += red[tid][i2];
      u64 raw = (u64)__float_as_uint(bmS[tid]) | ((u64)__float_as_uint(s8) << 32);
      u64* Gp = G + (((size_t)(t - 1) * BB + b) * NJB + j) * KC + tid;
      __hip_atomic_store(Gp, raw, __ATOMIC_RELAXED, __HIP_MEMORY_SCOPE_AGENT);
    }
    // publish: drain this block's G stores (scoped stores are vm ops; the
    // pre-barrier s_waitcnt vmcnt(0) completes them at the coherence point),
    // then set the ready flag. Monotonic -> no reset hazard, no fences.
    __syncthreads();
    if (tid == 0) {
      unsigned* fl = flags + ((size_t)(t - 1) * BB + b) * NJB + j;
      __hip_atomic_store(fl, 1u, __ATOMIC_RELAXED, __HIP_MEMORY_SCOPE_AGENT);
    }
  }

  // ---- loss: u currently holds u25 (computed from v24 in iteration 25)
  if (tid < NJB) {
    const unsigned* fp = flags + ((size_t)24 * BB + b) * NJB;
    while (__hip_atomic_load(&fp[tid], __ATOMIC_RELAXED, __HIP_MEMORY_SCOPE_AGENT) == 0u)
      __builtin_amdgcn_s_sleep(1);
  }
  __syncthreads();
  __shared__ float v25S[KC];
  if (tid < KC) {
    const u64* Gp = G + (((size_t)24 * BB + b) * NJB) * KC;
    float gm[NJB], gs[NJB];
#pragma unroll
    for (int jj = 0; jj < NJB; jj++) {
      u64 raw = __hip_atomic_load(&Gp[jj * KC + tid], __ATOMIC_RELAXED, __HIP_MEMORY_SCOPE_AGENT);
      gm[jj] = __uint_as_float((unsigned)raw);
      gs[jj] = __uint_as_float((unsigned)(raw >> 32));
    }
    float m = -1e30f;
#pragma unroll
    for (int jj = 0; jj < NJB; jj++) m = fmaxf(m, gm[jj]);
    float s = 0.f;
#pragma unroll
    for (int jj = 0; jj < NJB; jj++) s += gs[jj] * expf(gm[jj] - m);
    v25S[tid] = EPS * logq - EPS * (m + logf(s));
  }
  __syncthreads();
  float lsev = lseArr[(size_t)b * NP + n];
  float part = 0.f;
#pragma unroll
  for (int k = 0; k < KC; k++) {
    float gamma = expf((u + v25S[k] - c[k]) * IEPS);
    float logsm = LSm[((size_t)b * KC + k) * NP + n] - lsev;
    part += gamma * logsm;
  }
  part *= (float)NP;
  int lane = tid & 63, wid = tid >> 6;
  part = waveReduceSum(part);
  if (lane == 0) redL[wid] = part;
  __syncthreads();
  if (tid == 0) {
    float tt = redL[0] + redL[1] + redL[2] + redL[3];
    atomicAdd(out0, -tt / (float)(BB * NP));
  }
}

// ---------------- tiled f32 conv1x1 GEMM (projector head, N=32 tiny)
template<int BM, int BN, int BK, int TM, int TN, bool BNRELU>
__global__ __launch_bounds__(256) void gemm_conv(
    const float* __restrict__ W, const float* __restrict__ bias,
    const float* __restrict__ X, float* __restrict__ Y,
    const float* __restrict__ bnscale, const float* __restrict__ bnshift,
    int M, int K, int N) {
  __shared__ float As[BK][BM + 4];
  __shared__ float Xs[BK][BN + 4];
  const int b = blockIdx.z;
  const int m0 = blockIdx.y * BM;
  const int n0 = blockIdx.x * BN;
  const int tid = threadIdx.x;
  const int tx = tid % (BN / TN);
  const int ty = tid / (BN / TN);
  const float* Xb = X + (size_t)b * K * N;
  float acc[TM][TN];
#pragma unroll
  for (int i = 0; i < TM; i++)
#pragma unroll
    for (int j = 0; j < TN; j++) acc[i][j] = 0.f;

  for (int k0 = 0; k0 < K; k0 += BK) {
    for (int i = tid; i < BM * BK; i += 256) {
      int r = i / BK, c = i % BK;
      As[c][r] = W[(size_t)(m0 + r) * K + k0 + c];
    }
    for (int i = tid; i < BK * BN; i += 256) {
      int r = i / BN, c = i % BN;
      float x = Xb[(size_t)(k0 + r) * N + n0 + c];
      if (BNRELU) x = fmaxf(fmaf(x, bnscale[k0 + r], bnshift[k0 + r]), 0.f);
      Xs[r][c] = x;
    }
    __syncthreads();
#pragma unroll 4
    for (int kk = 0; kk < BK; kk++) {
      float ra[TM], rb[TN];
#pragma unroll
      for (int i = 0; i < TM; i++) ra[i] = As[kk][ty * TM + i];
#pragma unroll
      for (int j = 0; j < TN; j++) rb[j] = Xs[kk][tx * TN + j];
#pragma unroll
      for (int i = 0; i < TM; i++)
#pragma unroll
        for (int j = 0; j < TN; j++) acc[i][j] = fmaf(ra[i], rb[j], acc[i][j]);
    }
    __syncthreads();
  }
#pragma unroll
  for (int i = 0; i < TM; i++) {
    float bm = bias[m0 + ty * TM + i];
#pragma unroll
    for (int j = 0; j < TN; j++)
      Y[((size_t)b * M + m0 + ty * TM + i) * N + n0 + tx * TN + j] = acc[i][j] + bm;
  }
}

// ---------------- tiny MLP gemm: one wave per output element
template<bool BNRELU>
__global__ __launch_bounds__(256) void mlp_gemm(
    const float* __restrict__ W, const float* __restrict__ bias,
    const float* __restrict__ in, float* __restrict__ out,
    const float* __restrict__ sc, const float* __restrict__ sh, int M, int K) {
  int gw = (blockIdx.x * 256 + threadIdx.x) >> 6;   // global wave id = output idx
  int lane = threadIdx.x & 63;
  int s = gw / M, jj = gw % M;
  const float4* ip = (const float4*)(in + (size_t)s * K);
  const float4* wp = (const float4*)(W + (size_t)jj * K);
  float acc = 0.f;
  for (int c4 = lane; c4 < (K >> 2); c4 += 64) {
    float4 x = ip[c4];
    float4 w = wp[c4];
    if (BNRELU) {
      int cb = c4 * 4;
      x.x = fmaxf(fmaf(x.x, sc[cb + 0], sh[cb + 0]), 0.f);
      x.y = fmaxf(fmaf(x.y, sc[cb + 1], sh[cb + 1]), 0.f);
      x.z = fmaxf(fmaf(x.z, sc[cb + 2], sh[cb + 2]), 0.f);
      x.w = fmaxf(fmaf(x.w, sc[cb + 3], sh[cb + 3]), 0.f);
    }
    acc += x.x * w.x + x.y * w.y + x.z * w.z + x.w * w.w;
  }
  acc = waveReduceSum(acc);
  if (lane == 0) out[gw] = acc + bias[jj];
}

__global__ __launch_bounds__(256) void mlp_bnstats(
    const float* __restrict__ mat, const float* __restrict__ g, const float* __restrict__ beta,
    float* __restrict__ scale, float* __restrict__ shift, int M) {
  int j = blockIdx.x * 256 + threadIdx.x;
  if (j >= M) return;
  float s = 0.f, sq = 0.f;
  for (int si = 0; si < BB; si++) { float v = mat[si * M + j]; s += v; sq += v * v; }
  float mean = s / (float)BB;
  float var = sq / (float)BB - mean * mean;
  float sc = g[j] / sqrtf(var + BN_EPS);
  scale[j] = sc; shift[j] = beta[j] - mean * sc;
}

// ---------------- launch ----------------
extern "C" void kernel_launch(void* const* d_in, const int* in_sizes, int n_in,
                              void* d_out, int out_size, void* d_ws, size_t ws_size,
                              hipStream_t stream) {
  const float* feat = (const float*)d_in[0];
  const float* cw1 = (const float*)d_in[1];  const float* cb1 = (const float*)d_in[2];
  const float* cg1 = (const float*)d_in[3];  const float* ct1 = (const float*)d_in[4];
  const float* cw2 = (const float*)d_in[5];  const float* cb2 = (const float*)d_in[6];
  const float* cg2 = (const float*)d_in[7];  const float* ct2 = (const float*)d_in[8];
  const float* cw3 = (const float*)d_in[9];  const float* cb3 = (const float*)d_in[10];
  const float* pw1 = (const float*)d_in[11]; const float* pb1 = (const float*)d_in[12];
  const float* pg1 = (const float*)d_in[13]; const float* pt1 = (const float*)d_in[14];
  const float* pw2 = (const float*)d_in[15]; const float* pb2 = (const float*)d_in[16];
  const float* pg2 = (const float*)d_in[17]; const float* pt2 = (const float*)d_in[18];
  const float* pw3 = (const float*)d_in[19]; const float* pb3 = (const float*)d_in[20];
  const float* mw1 = (const float*)d_in[21]; const float* mb1 = (const float*)d_in[22];
  const float* mg1 = (const float*)d_in[23]; const float* mt1 = (const float*)d_in[24];
  const float* mw2 = (const float*)d_in[25]; const float* mb2 = (const float*)d_in[26];
  const float* mg2 = (const float*)d_in[27]; const float* mt2 = (const float*)d_in[28];
  const float* mw3 = (const float*)d_in[29]; const float* mb3 = (const float*)d_in[30];
  float* out = (float*)d_out;

  // ---- workspace layout: post-GEMM2 buffers alias Y1 ----
  char* p = (char*)d_ws;
  size_t off = 0;
  auto alloc = [&](size_t bytes) { char* r = p + off; off = (off + bytes + 255) & ~(size_t)255; return r; };
  float* Y1 = (float*)alloc(67108864);   // [8][512][4096] f32
  float* Y2 = (float*)alloc(67108864);
  u16* W1H = (u16*)alloc(1048576); u16* W1M = (u16*)alloc(1048576); u16* W1L = (u16*)alloc(1048576);
  u16* W2H = (u16*)alloc(524288);  u16* W2M = (u16*)alloc(524288);  u16* W2L = (u16*)alloc(524288);
  u16* W3H = (u16*)alloc(32768);   u16* W3M = (u16*)alloc(32768);   u16* W3L = (u16*)alloc(32768);
  float* SC1  = (float*)alloc(2048); float* SH1 = (float*)alloc(2048);
  float* SC2  = (float*)alloc(2048); float* SH2 = (float*)alloc(2048);
  float* PSC1 = (float*)alloc(2048); float* PSH1 = (float*)alloc(2048);
  float* PSC2 = (float*)alloc(2048); float* PSH2 = (float*)alloc(2048);
  float* MSC1 = (float*)alloc(2048); float* MSH1 = (float*)alloc(2048);
  float* MSC2 = (float*)alloc(2048); float* MSH2 = (float*)alloc(2048);
  // ---- sub-arena inside Y1's region: first written AFTER GEMM2 completes ----
  char* q = (char*)Y1;
  size_t qoff = 0;
  auto qalloc = [&](size_t bytes) { char* r = q + qoff; qoff = (qoff + bytes + 255) & ~(size_t)255; return r; };
  float* LSC  = (float*)qalloc(4194304);  // [8][32][4096], written by GEMM3
  float* SCRB = (float*)qalloc(4194304);  // score
  float* LSE  = (float*)qalloc(131072);
  u64*   GBUF = (u64*)qalloc(819200);     // 25*8*16*32 u64 pairs
  float* GMAX = (float*)qalloc(32768);
  float* MH1  = (float*)qalloc(16384);
  float* MH2  = (float*)qalloc(16384);
  float* T1   = (float*)qalloc(524288);
  float* T2   = (float*)qalloc(524288);
  // contiguous memset region: PIRAW | VLAD | COSTD | NFSQ | NMUSQ | FLAGS(16KB)
  const size_t MS_BYTES = 1024 + 1048576 + 4194304 + 131072 + 1024 + 16384;
  char* MS = qalloc(MS_BYTES);
  float* PIRAW = (float*)MS;
  float* VLAD  = (float*)(MS + 1024);
  float* COSTD = (float*)(MS + 1024 + 1048576);
  float* NFSQ  = (float*)(MS + 1024 + 1048576 + 4194304);
  float* NMUSQ = (float*)(MS + 1024 + 1048576 + 4194304 + 131072);
  unsigned* FLG = (unsigned*)(MS + 1024 + 1048576 + 4194304 + 131072 + 1024);

  hipMemsetAsync(d_out, 0, sizeof(float), stream);

  float logp = logf(1.0f / NP + 1e-8f);
  float logq = logf(1.0f / KC + 1e-8f);
  dim3 blk(256);

  // weight permute + 3-split (all three sets, one launch)
  convW3_all<<<dim3(4, 32, 3), blk, 0, stream>>>(
      cw1, W1H, W1M, W1L, cw2, W2H, W2M, W2L, cw3, W3H, W3M, W3L);

  // score head: bf16x3 MFMA (f32-equivalent), reg-prefetch pipelined
  gemm_mfma3<128, 4, 4, 4, 2, false><<<dim3(128, 1, 8), blk, 0, stream>>>(
      W1H, W1M, W1L, cb1, feat, nullptr, nullptr, Y1, 1024, 512);
  bnstats<<<dim3(512), blk, 0, stream>>>(Y1, cg1, ct1, SC1, SH1, 512, NP);
  gemm_mfma3<128, 4, 4, 4, 2, true><<<dim3(128, 1, 8), blk, 0, stream>>>(
      W2H, W2M, W2L, cb2, Y1, SC1, SH1, Y2, 512, 512);
  bnstats<<<dim3(512), blk, 0, stream>>>(Y2, cg2, ct2, SC2, SH2, 512, NP);
  // Y1 is now dead -> zero the aliased accumulation buffers inside it
  hipMemsetAsync(MS, 0, MS_BYTES, stream);
  gemm_mfma3<32, 1, 2, 2, 1, true><<<dim3(32, 1, 8), blk, 0, stream>>>(
      W3H, W3M, W3L, cb3, Y2, SC2, SH2, LSC, 512, 32);

  // softmax + pi + lse
  softmax_pi<<<dim3(BB * NP / 256), blk, 0, stream>>>(LSC, SCRB, LSE, PIRAW);

  // vlad (+ fused ||mu||^2)
  vlad_accum<<<dim3(8, DD / 128, BB), blk, 0, stream>>>(feat, SCRB, VLAD);
  vlad_fin<<<dim3(BB * DD / 256), blk, 0, stream>>>(VLAD, PIRAW, GMAX, NMUSQ);

  // cost dots (+ fused ||f||^2)
  cost_accum<<<dim3(4, NP / 128, BB), blk, 0, stream>>>(feat, VLAD, COSTD, NFSQ);

  // fused sinkhorn: normalize + 25 iterations + loss in ONE launch
  // (8B scoped-atomic G exchange + per-(t,b,j) ready-flags; no fences)
  sinkhorn_all<<<dim3(BB * NJB), blk, 0, stream>>>(
      COSTD, NFSQ, NMUSQ, GBUF, LSC, LSE, out, FLG, logp, logq);

  // predictor MLP on max-pooled vlad (wave-per-output, multi-block)
  mlp_gemm<false><<<dim3(BB * HH / 4), blk, 0, stream>>>(mw1, mb1, GMAX, MH1, nullptr, nullptr, HH, DD);
  mlp_bnstats<<<dim3(2), blk, 0, stream>>>(MH1, mg1, mt1, MSC1, MSH1, HH);
  mlp_gemm<true><<<dim3(BB * HH / 4), blk, 0, stream>>>(mw2, mb2, MH1, MH2, MSC1, MSH1, HH, HH);
  mlp_bnstats<<<dim3(2), blk, 0, stream>>>(MH2, mg2, mt2, MSC2, MSH2, HH);
  mlp_gemm<true><<<dim3(BB * PP / 4), blk, 0, stream>>>(mw3, mb3, MH2, out + 1 + BB * PP * KC, MSC2, MSH2, PP, HH);

  // projector conv head on vlad (N=32, f32)
  gemm_conv<64, 32, 16, 4, 2, false><<<dim3(1, HH / 64, BB), blk, 0, stream>>>(pw1, pb1, VLAD, T1, nullptr, nullptr, HH, DD, KC);
  bnstats<<<dim3(512), blk, 0, stream>>>(T1, pg1, pt1, PSC1, PSH1, HH, KC);
  gemm_conv<64, 32, 16, 4, 2, true><<<dim3(1, HH / 64, BB), blk, 0, stream>>>(pw2, pb2, T1, T2, PSC1, PSH1, HH, HH, KC);
  bnstats<<<dim3(512), blk, 0, stream>>>(T2, pg2, pt2, PSC2, PSH2, HH, KC);
  gemm_conv<64, 32, 16, 4, 2, true><<<dim3(1, PP / 64, BB), blk, 0, stream>>>(pw3, pb3, T2, out + 1, PSC2, PSH2, PP, HH, KC);
}